// Round 2
// baseline (579.294 us; speedup 1.0000x reference)
//
#include <hip/hip_runtime.h>

// TransformerBlock: x = x + attn(rms(x)); x = x + mlp(rms(x))
// B=2, S=2048, D=1024, H=16, dh=64, EXP=4. Inputs/outputs fp32; internal bf16 MFMA.

typedef __attribute__((ext_vector_type(8))) short short8;   // 8 x bf16 = 4 VGPR
typedef __attribute__((ext_vector_type(4))) float floatx4;  // MFMA 16x16 acc

#define EPI_NONE 0
#define EPI_RES  1
#define EPI_GATE 2

__device__ __forceinline__ float b2f(unsigned short u) {
  union { unsigned int i; float f; } c; c.i = ((unsigned int)u) << 16; return c.f;
}
__device__ __forceinline__ unsigned short f2b(float f) {
  union { float f; unsigned int u; } c; c.f = f;
  unsigned int r = 0x7fffu + ((c.u >> 16) & 1u);
  return (unsigned short)((c.u + r) >> 16);
}

__device__ __forceinline__ void load_lds16(const void* g, void* l) {
  __builtin_amdgcn_global_load_lds(
      (const __attribute__((address_space(1))) unsigned int*)g,
      (__attribute__((address_space(3))) unsigned int*)l, 16, 0, 0);
}

// ---------------- fp32 -> bf16 convert (weights) ----------------
__global__ __launch_bounds__(256)
void cvt_kernel(const float* __restrict__ in, unsigned short* __restrict__ out, int n4) {
  int i = blockIdx.x * 256 + threadIdx.x;
  if (i >= n4) return;
  float4 v = ((const float4*)in)[i];
  ushort4 o;
  o.x = f2b(v.x); o.y = f2b(v.y); o.z = f2b(v.z); o.w = f2b(v.w);
  ((ushort4*)out)[i] = o;
}

// ---------------- RMSNorm: one block per row of 1024, fp32 in -> bf16 out ----------------
__global__ __launch_bounds__(256)
void rmsnorm_kernel(const float* __restrict__ x,
                    const float* __restrict__ scale,
                    unsigned short* __restrict__ y) {
  const int row = blockIdx.x;
  const int tid = threadIdx.x;
  const int base = row * 1024 + tid * 4;
  float4 v = *(const float4*)(x + base);
  float ss = v.x*v.x + v.y*v.y + v.z*v.z + v.w*v.w;
#pragma unroll
  for (int d = 32; d > 0; d >>= 1) ss += __shfl_down(ss, d);
  __shared__ float red[4];
  const int wave = tid >> 6, lane = tid & 63;
  if (lane == 0) red[wave] = ss;
  __syncthreads();
  float tot = red[0] + red[1] + red[2] + red[3];
  float rs = rsqrtf(tot * (1.0f/1024.0f) + 1e-6f);
  float4 sv = *(const float4*)(scale + tid * 4);
  ushort4 o;
  o.x = f2b(v.x * rs * sv.x);
  o.y = f2b(v.y * rs * sv.y);
  o.z = f2b(v.z * rs * sv.z);
  o.w = f2b(v.w * rs * sv.w);
  *(ushort4*)(y + base) = o;
}

// ---------------- GEMM: C[M,N] = A[M,K] @ B[N,K]^T (m97 structure) ----------------
// 128x128 tile, BK=32, 4 waves each 64x64 (4x4 of 16x16x32 MFMA).
// OutT: float (store fp32) or unsigned short (store bf16).
// EPI_RES: C = acc + R (R fp32). EPI_GATE: C = R * silu(acc) (R bf16, may alias C).
template<int EPI, typename OutT, typename ResT>
__global__ __launch_bounds__(256)
void gemm_bt(const unsigned short* __restrict__ A,
             const unsigned short* __restrict__ B,
             OutT* C, const ResT* R, int M, int N, int K) {
  __shared__ __align__(16) unsigned short As[128 * 32];
  __shared__ __align__(16) unsigned short Bs[128 * 32];
  const int tid = threadIdx.x;
  const int wave = tid >> 6;
  const int lane = tid & 63;
  const int m0 = blockIdx.y * 128;
  const int n0 = blockIdx.x * 128;
  const int wm = (wave & 1) * 64;
  const int wn = (wave >> 1) * 64;
  const int frow = lane & 15;        // A-row / B-col within 16-tile
  const int fk = (lane >> 4) * 8;    // k offset within 32

  floatx4 acc[4][4];
#pragma unroll
  for (int i = 0; i < 4; ++i)
#pragma unroll
    for (int j = 0; j < 4; ++j) acc[i][j] = (floatx4){0.f, 0.f, 0.f, 0.f};

  // staging: 1 KiB segment per wave-issue; lane l -> byte offset 16*l within segment
  const int srow = lane >> 2;
  const int scol = (lane & 3) * 8;
  const unsigned short* Ag  = A + (size_t)(m0 + wave * 16 + srow) * K + scol;
  const unsigned short* Ag2 = A + (size_t)(m0 + (wave + 4) * 16 + srow) * K + scol;
  const unsigned short* Bg  = B + (size_t)(n0 + wave * 16 + srow) * K + scol;
  const unsigned short* Bg2 = B + (size_t)(n0 + (wave + 4) * 16 + srow) * K + scol;

  for (int k0 = 0; k0 < K; k0 += 32) {
    __syncthreads();
    load_lds16(Ag + k0,  &As[wave * 512]);
    load_lds16(Ag2 + k0, &As[(wave + 4) * 512]);
    load_lds16(Bg + k0,  &Bs[wave * 512]);
    load_lds16(Bg2 + k0, &Bs[(wave + 4) * 512]);
    __syncthreads();
    short8 af[4], bf[4];
#pragma unroll
    for (int i = 0; i < 4; ++i) af[i] = *(const short8*)&As[(wm + 16*i + frow)*32 + fk];
#pragma unroll
    for (int j = 0; j < 4; ++j) bf[j] = *(const short8*)&Bs[(wn + 16*j + frow)*32 + fk];
#pragma unroll
    for (int i = 0; i < 4; ++i)
#pragma unroll
      for (int j = 0; j < 4; ++j)
        acc[i][j] = __builtin_amdgcn_mfma_f32_16x16x32_bf16(af[i], bf[j], acc[i][j], 0, 0, 0);
  }

  // epilogue: C row = (lane>>4)*4 + r, col = lane&15 (verified m89/m91 layout)
  const int g4 = (lane >> 4) * 4;
#pragma unroll
  for (int i = 0; i < 4; ++i) {
#pragma unroll
    for (int r = 0; r < 4; ++r) {
      const int row = m0 + wm + 16*i + g4 + r;
#pragma unroll
      for (int j = 0; j < 4; ++j) {
        const int col = n0 + wn + 16*j + frow;
        const size_t idx = (size_t)row * N + col;
        float v = acc[i][j][r];
        if constexpr (EPI == EPI_RES) {
          v += (float)R[idx];                      // R fp32
        } else if constexpr (EPI == EPI_GATE) {
          float up = b2f((unsigned short)R[idx]);  // R = up-projection bf16 (aliases C)
          v = up * (v / (1.f + __expf(-v)));       // up * silu(gate)
        }
        if constexpr (sizeof(OutT) == 4) C[idx] = v;
        else                             C[idx] = f2b(v);
      }
    }
  }
}

// ---------------- Flash attention (causal), dh=64 ----------------
// grid: (S/128, B*H). block 256 = 4 waves; wave w owns 32 q-rows.
__global__ __launch_bounds__(256)
void attn_kernel(const unsigned short* __restrict__ qkv,  // [B*S, 3072] bf16
                 unsigned short* __restrict__ out) {      // [B*S, 1024] bf16
  const int qb = blockIdx.x;
  const int bh = blockIdx.y;
  const int b = bh >> 4, h = bh & 15;
  const int tid = threadIdx.x, wave = tid >> 6, lane = tid & 63;
  const int frow = lane & 15, fk = (lane >> 4) * 8, g4 = (lane >> 4) * 4;

  __shared__ __align__(16) unsigned short vt[64 * 136];      // V^T [dd][key], pad 136
  __shared__ __align__(16) unsigned short pl[4 * 32 * 136];  // P per wave [32][key]

  const unsigned short* Qb = qkv + (size_t)(b * 2048) * 3072 + h * 64;
  const unsigned short* Kb = Qb + 1024;
  const unsigned short* Vb = Qb + 2048;

  short8 qf[2][2];
  const int qrow0 = qb * 128 + wave * 32;
#pragma unroll
  for (int i = 0; i < 2; ++i)
#pragma unroll
    for (int kq = 0; kq < 2; ++kq)
      qf[i][kq] = *(const short8*)(Qb + (size_t)(qrow0 + 16*i + frow) * 3072 + kq * 32 + fk);

  float m_s[2][4], l_s[2][4];
  floatx4 o[2][4];
#pragma unroll
  for (int i = 0; i < 2; ++i)
#pragma unroll
    for (int r = 0; r < 4; ++r) { m_s[i][r] = -1e30f; l_s[i][r] = 0.f; }
#pragma unroll
  for (int i = 0; i < 2; ++i)
#pragma unroll
    for (int jt = 0; jt < 4; ++jt) o[i][jt] = (floatx4){0.f, 0.f, 0.f, 0.f};

  const int vkey = tid & 127;
  const int vdd = (tid >> 7) * 32;

  for (int kb = 0; kb <= qb; ++kb) {
    __syncthreads();  // protect prior iteration's LDS reads
    const unsigned short* vrow = Vb + (size_t)(kb * 128 + vkey) * 3072 + vdd;
#pragma unroll
    for (int c = 0; c < 4; ++c) {
      short8 vv = *(const short8*)(vrow + c * 8);
#pragma unroll
      for (int e = 0; e < 8; ++e)
        vt[(vdd + c * 8 + e) * 136 + vkey] = (unsigned short)vv[e];
    }
    __syncthreads();

    floatx4 s[2][8];
#pragma unroll
    for (int i = 0; i < 2; ++i)
#pragma unroll
      for (int j = 0; j < 8; ++j) s[i][j] = (floatx4){0.f, 0.f, 0.f, 0.f};
#pragma unroll
    for (int j = 0; j < 8; ++j) {
      const unsigned short* kp = Kb + (size_t)(kb * 128 + 16*j + frow) * 3072 + fk;
      short8 kf0 = *(const short8*)(kp);
      short8 kf1 = *(const short8*)(kp + 32);
#pragma unroll
      for (int i = 0; i < 2; ++i) {
        s[i][j] = __builtin_amdgcn_mfma_f32_16x16x32_bf16(qf[i][0], kf0, s[i][j], 0, 0, 0);
        s[i][j] = __builtin_amdgcn_mfma_f32_16x16x32_bf16(qf[i][1], kf1, s[i][j], 0, 0, 0);
      }
    }
    const bool diag = (kb == qb);
#pragma unroll
    for (int i = 0; i < 2; ++i)
#pragma unroll
      for (int j = 0; j < 8; ++j)
#pragma unroll
        for (int r = 0; r < 4; ++r) {
          float v = s[i][j][r] * 0.125f;
          if (diag) {
            int qq = wave * 32 + 16*i + g4 + r;
            int kk = 16*j + frow;
            if (kk > qq) v = -1e30f;
          }
          s[i][j][r] = v;
        }
#pragma unroll
    for (int i = 0; i < 2; ++i)
#pragma unroll
      for (int r = 0; r < 4; ++r) {
        float mx = s[i][0][r];
#pragma unroll
        for (int j = 1; j < 8; ++j) mx = fmaxf(mx, s[i][j][r]);
        mx = fmaxf(mx, __shfl_xor(mx, 1));
        mx = fmaxf(mx, __shfl_xor(mx, 2));
        mx = fmaxf(mx, __shfl_xor(mx, 4));
        mx = fmaxf(mx, __shfl_xor(mx, 8));
        float mnew = fmaxf(m_s[i][r], mx);
        float alpha = __expf(m_s[i][r] - mnew);
        m_s[i][r] = mnew;
        float rs = 0.f;
#pragma unroll
        for (int j = 0; j < 8; ++j) {
          float p = __expf(s[i][j][r] - mnew);
          s[i][j][r] = p;
          rs += p;
        }
        rs += __shfl_xor(rs, 1);
        rs += __shfl_xor(rs, 2);
        rs += __shfl_xor(rs, 4);
        rs += __shfl_xor(rs, 8);
        l_s[i][r] = l_s[i][r] * alpha + rs;
#pragma unroll
        for (int jt = 0; jt < 4; ++jt) o[i][jt][r] *= alpha;
      }
    unsigned short* pw = pl + wave * 32 * 136;
#pragma unroll
    for (int i = 0; i < 2; ++i)
#pragma unroll
      for (int j = 0; j < 8; ++j)
#pragma unroll
        for (int r = 0; r < 4; ++r)
          pw[(16*i + g4 + r) * 136 + 16*j + frow] = f2b(s[i][j][r]);
    __syncthreads();
#pragma unroll
    for (int kk = 0; kk < 4; ++kk) {
      short8 pa[2], vb2[4];
#pragma unroll
      for (int i = 0; i < 2; ++i)
        pa[i] = *(const short8*)&pl[(wave * 32 + 16*i + frow) * 136 + kk * 32 + fk];
#pragma unroll
      for (int jt = 0; jt < 4; ++jt)
        vb2[jt] = *(const short8*)&vt[(16*jt + frow) * 136 + kk * 32 + fk];
#pragma unroll
      for (int i = 0; i < 2; ++i)
#pragma unroll
        for (int jt = 0; jt < 4; ++jt)
          o[i][jt] = __builtin_amdgcn_mfma_f32_16x16x32_bf16(pa[i], vb2[jt], o[i][jt], 0, 0, 0);
    }
  }

#pragma unroll
  for (int i = 0; i < 2; ++i)
#pragma unroll
    for (int jt = 0; jt < 4; ++jt)
#pragma unroll
      for (int r = 0; r < 4; ++r) {
        int row = b * 2048 + qb * 128 + wave * 32 + 16*i + g4 + r;
        int col = h * 64 + 16*jt + frow;
        out[(size_t)row * 1024 + col] = f2b(o[i][jt][r] / l_s[i][r]);
      }
}

// ---------------- launcher ----------------
extern "C" void kernel_launch(void* const* d_in, const int* in_sizes, int n_in,
                              void* d_out, int out_size, void* d_ws, size_t ws_size,
                              hipStream_t stream) {
  const float* x      = (const float*)d_in[0];   // [2,2048,1024]
  const float* w_qkv  = (const float*)d_in[1];   // [3072,1024]
  const float* w_o    = (const float*)d_in[2];   // [1024,1024]
  const float* w_up   = (const float*)d_in[3];   // [4096,1024]
  const float* w_gate = (const float*)d_in[4];   // [4096,1024]
  const float* w_down = (const float*)d_in[5];   // [1024,4096]
  const float* scale1 = (const float*)d_in[6];
  const float* scale2 = (const float*)d_in[7];

  char* ws = (char*)d_ws;
  unsigned short* wq_b = (unsigned short*)(ws);                 //  6,291,456 B
  unsigned short* wo_b = (unsigned short*)(ws +  6291456);      //  2,097,152 B
  unsigned short* wu_b = (unsigned short*)(ws +  8388608);      //  8,388,608 B
  unsigned short* wg_b = (unsigned short*)(ws + 16777216);      //  8,388,608 B
  unsigned short* wd_b = (unsigned short*)(ws + 25165824);      //  8,388,608 B
  unsigned short* qkv  = (unsigned short*)(ws + 33554432);      // 25,165,824 B (bf16)
  unsigned short* hup  = (unsigned short*)(ws + 33554432);      // 33,554,432 B (aliases qkv; disjoint lifetime)
  unsigned short* xn   = (unsigned short*)(ws + 67108864);      //  8,388,608 B (bf16)
  unsigned short* attnb= (unsigned short*)(ws + 75497472);      //  8,388,608 B (bf16)
  float*          x1   = (float*)         (ws + 83886080);      // 16,777,216 B (fp32)
  float*          outp = (float*)d_out;                         // fp32

  const int M = 4096;
  dim3 blk(256);

  // weights fp32 -> bf16
  cvt_kernel<<<(3145728/4 + 255)/256, blk, 0, stream>>>(w_qkv,  wq_b, 3145728/4);
  cvt_kernel<<<(1048576/4 + 255)/256, blk, 0, stream>>>(w_o,    wo_b, 1048576/4);
  cvt_kernel<<<(4194304/4 + 255)/256, blk, 0, stream>>>(w_up,   wu_b, 4194304/4);
  cvt_kernel<<<(4194304/4 + 255)/256, blk, 0, stream>>>(w_gate, wg_b, 4194304/4);
  cvt_kernel<<<(4194304/4 + 255)/256, blk, 0, stream>>>(w_down, wd_b, 4194304/4);

  // x1 = x + W_o( attn( rms(x) ) )
  rmsnorm_kernel<<<4096, blk, 0, stream>>>(x, scale1, xn);
  gemm_bt<EPI_NONE, unsigned short, unsigned short>
      <<<dim3(24, 32), blk, 0, stream>>>(xn, wq_b, qkv, (const unsigned short*)nullptr, M, 3072, 1024);
  attn_kernel<<<dim3(16, 32), blk, 0, stream>>>(qkv, attnb);
  gemm_bt<EPI_RES, float, float>
      <<<dim3(8, 32), blk, 0, stream>>>(attnb, wo_b, x1, x, M, 1024, 1024);

  // out = x1 + W_down( up(rms(x1)) * silu(gate(rms(x1))) )
  rmsnorm_kernel<<<4096, blk, 0, stream>>>(x1, scale2, xn);
  gemm_bt<EPI_NONE, unsigned short, unsigned short>
      <<<dim3(32, 32), blk, 0, stream>>>(xn, wu_b, hup, (const unsigned short*)nullptr, M, 4096, 1024);
  gemm_bt<EPI_GATE, unsigned short, unsigned short>
      <<<dim3(32, 32), blk, 0, stream>>>(xn, wg_b, hup, hup, M, 4096, 1024);
  gemm_bt<EPI_RES, float, float>
      <<<dim3(8, 32), blk, 0, stream>>>(hup, wd_b, outp, x1, M, 1024, 4096);

  (void)in_sizes; (void)n_in; (void)out_size; (void)ws_size;
}

// Round 3
// 563.245 us; speedup vs baseline: 1.0285x; 1.0285x over previous
//
#include <hip/hip_runtime.h>

// TransformerBlock: x = x + attn(rms(x)); x = x + mlp(rms(x))
// B=2, S=2048, D=1024, H=16, dh=64, EXP=4. Inputs/outputs fp32; internal bf16 MFMA.

typedef __attribute__((ext_vector_type(8))) short short8;   // 8 x bf16 = 4 VGPR
typedef __attribute__((ext_vector_type(4))) float floatx4;  // MFMA 16x16 acc

#define EPI_NONE 0
#define EPI_RES  1
#define EPI_GATE 2

__device__ __forceinline__ float b2f(unsigned short u) {
  union { unsigned int i; float f; } c; c.i = ((unsigned int)u) << 16; return c.f;
}
__device__ __forceinline__ unsigned short f2b(float f) {
  union { float f; unsigned int u; } c; c.f = f;
  unsigned int r = 0x7fffu + ((c.u >> 16) & 1u);
  return (unsigned short)((c.u + r) >> 16);
}

__device__ __forceinline__ void load_lds16(const void* g, void* l) {
  __builtin_amdgcn_global_load_lds(
      (const __attribute__((address_space(1))) unsigned int*)g,
      (__attribute__((address_space(3))) unsigned int*)l, 16, 0, 0);
}

// ---------------- fp32 -> bf16 convert (weights) ----------------
__global__ __launch_bounds__(256)
void cvt_kernel(const float* __restrict__ in, unsigned short* __restrict__ out, int n4) {
  int i = blockIdx.x * 256 + threadIdx.x;
  if (i >= n4) return;
  float4 v = ((const float4*)in)[i];
  ushort4 o;
  o.x = f2b(v.x); o.y = f2b(v.y); o.z = f2b(v.z); o.w = f2b(v.w);
  ((ushort4*)out)[i] = o;
}

// ---------------- RMSNorm: one block per row of 1024, fp32 in -> bf16 out ----------------
__global__ __launch_bounds__(256)
void rmsnorm_kernel(const float* __restrict__ x,
                    const float* __restrict__ scale,
                    unsigned short* __restrict__ y) {
  const int row = blockIdx.x;
  const int tid = threadIdx.x;
  const int base = row * 1024 + tid * 4;
  float4 v = *(const float4*)(x + base);
  float ss = v.x*v.x + v.y*v.y + v.z*v.z + v.w*v.w;
#pragma unroll
  for (int d = 32; d > 0; d >>= 1) ss += __shfl_down(ss, d);
  __shared__ float red[4];
  const int wave = tid >> 6, lane = tid & 63;
  if (lane == 0) red[wave] = ss;
  __syncthreads();
  float tot = red[0] + red[1] + red[2] + red[3];
  float rs = rsqrtf(tot * (1.0f/1024.0f) + 1e-6f);
  float4 sv = *(const float4*)(scale + tid * 4);
  ushort4 o;
  o.x = f2b(v.x * rs * sv.x);
  o.y = f2b(v.y * rs * sv.y);
  o.z = f2b(v.z * rs * sv.z);
  o.w = f2b(v.w * rs * sv.w);
  *(ushort4*)(y + base) = o;
}

// ---------------- GEMM: C[M,N] = A[M,K] @ B[N,K]^T (m97 structure) ----------------
template<int EPI, typename OutT, typename ResT>
__global__ __launch_bounds__(256)
void gemm_bt(const unsigned short* __restrict__ A,
             const unsigned short* __restrict__ B,
             OutT* C, const ResT* R, int M, int N, int K) {
  __shared__ __align__(16) unsigned short As[128 * 32];
  __shared__ __align__(16) unsigned short Bs[128 * 32];
  const int tid = threadIdx.x;
  const int wave = tid >> 6;
  const int lane = tid & 63;
  const int m0 = blockIdx.y * 128;
  const int n0 = blockIdx.x * 128;
  const int wm = (wave & 1) * 64;
  const int wn = (wave >> 1) * 64;
  const int frow = lane & 15;
  const int fk = (lane >> 4) * 8;

  floatx4 acc[4][4];
#pragma unroll
  for (int i = 0; i < 4; ++i)
#pragma unroll
    for (int j = 0; j < 4; ++j) acc[i][j] = (floatx4){0.f, 0.f, 0.f, 0.f};

  const int srow = lane >> 2;
  const int scol = (lane & 3) * 8;
  const unsigned short* Ag  = A + (size_t)(m0 + wave * 16 + srow) * K + scol;
  const unsigned short* Ag2 = A + (size_t)(m0 + (wave + 4) * 16 + srow) * K + scol;
  const unsigned short* Bg  = B + (size_t)(n0 + wave * 16 + srow) * K + scol;
  const unsigned short* Bg2 = B + (size_t)(n0 + (wave + 4) * 16 + srow) * K + scol;

  for (int k0 = 0; k0 < K; k0 += 32) {
    __syncthreads();
    load_lds16(Ag + k0,  &As[wave * 512]);
    load_lds16(Ag2 + k0, &As[(wave + 4) * 512]);
    load_lds16(Bg + k0,  &Bs[wave * 512]);
    load_lds16(Bg2 + k0, &Bs[(wave + 4) * 512]);
    __syncthreads();
    short8 af[4], bf[4];
#pragma unroll
    for (int i = 0; i < 4; ++i) af[i] = *(const short8*)&As[(wm + 16*i + frow)*32 + fk];
#pragma unroll
    for (int j = 0; j < 4; ++j) bf[j] = *(const short8*)&Bs[(wn + 16*j + frow)*32 + fk];
#pragma unroll
    for (int i = 0; i < 4; ++i)
#pragma unroll
      for (int j = 0; j < 4; ++j)
        acc[i][j] = __builtin_amdgcn_mfma_f32_16x16x32_bf16(af[i], bf[j], acc[i][j], 0, 0, 0);
  }

  const int g4 = (lane >> 4) * 4;
#pragma unroll
  for (int i = 0; i < 4; ++i) {
#pragma unroll
    for (int r = 0; r < 4; ++r) {
      const int row = m0 + wm + 16*i + g4 + r;
#pragma unroll
      for (int j = 0; j < 4; ++j) {
        const int col = n0 + wn + 16*j + frow;
        const size_t idx = (size_t)row * N + col;
        float v = acc[i][j][r];
        if constexpr (EPI == EPI_RES) {
          v += (float)R[idx];
        } else if constexpr (EPI == EPI_GATE) {
          float up = b2f((unsigned short)R[idx]);
          v = up * (v / (1.f + __expf(-v)));
        }
        if constexpr (sizeof(OutT) == 4) C[idx] = v;
        else                             C[idx] = f2b(v);
      }
    }
  }
}

// ---------------- Flash attention (causal), dh=64 ----------------
// grid: 512 blocks 1D; decode bh = id&31, q_idx = id>>5, qb swizzled so the
// two co-resident blocks per CU (id, id+256) have complementary work:
// pairs (2q, 15-2q) -> 17 kb-iterations per CU under round-robin dispatch.
__global__ __launch_bounds__(256)
void attn_kernel(const unsigned short* __restrict__ qkv,  // [B*S, 3072] bf16
                 unsigned short* __restrict__ out) {      // [B*S, 1024] bf16
  const int lin = blockIdx.x;
  const int bh = lin & 31;
  const int q_idx = lin >> 5;
  const int qb = (q_idx < 8) ? (2 * q_idx) : (31 - 2 * q_idx);
  const int b = bh >> 4, h = bh & 15;
  const int tid = threadIdx.x, wave = tid >> 6, lane = tid & 63;
  const int frow = lane & 15, fk = (lane >> 4) * 8, g4 = (lane >> 4) * 4;

  __shared__ __align__(16) unsigned short Ks[2 * 128 * 32];  // [kq][key][32] 16 KB
  __shared__ __align__(16) unsigned short vt[64 * 136];      // V^T [dd][key], pad 136
  __shared__ __align__(16) unsigned short pl[4 * 32 * 136];  // P per wave [32][key]

  const unsigned short* Qb = qkv + (size_t)(b * 2048) * 3072 + h * 64;
  const unsigned short* Kb = Qb + 1024;
  const unsigned short* Vb = Qb + 2048;

  // Q fragments in registers (A-operand: row=lane&15, k=(lane>>4)*8)
  short8 qf[2][2];
  const int qrow0 = qb * 128 + wave * 32;
#pragma unroll
  for (int i = 0; i < 2; ++i)
#pragma unroll
    for (int kq = 0; kq < 2; ++kq)
      qf[i][kq] = *(const short8*)(Qb + (size_t)(qrow0 + 16*i + frow) * 3072 + kq * 32 + fk);

  float m_s[2][4], l_s[2][4];
  floatx4 o[2][4];
#pragma unroll
  for (int i = 0; i < 2; ++i)
#pragma unroll
    for (int r = 0; r < 4; ++r) { m_s[i][r] = -1e30f; l_s[i][r] = 0.f; }
#pragma unroll
  for (int i = 0; i < 2; ++i)
#pragma unroll
    for (int jt = 0; jt < 4; ++jt) o[i][jt] = (floatx4){0.f, 0.f, 0.f, 0.f};

  const int srow = lane >> 2;        // staging row within 16-row segment
  const int scol = (lane & 3) * 8;   // staging col (halves) within 32
  const int vkey = tid & 127;
  const int vdd = (tid >> 7) * 32;

  for (int kb = 0; kb <= qb; ++kb) {
    __syncthreads();  // protect prior iteration's Ks/vt reads
    // stage K rows [wave*32, +32) of both kq slabs via global_load_lds
    const unsigned short* Ksrc = Kb + (size_t)(kb * 128 + wave * 32) * 3072;
#pragma unroll
    for (int kq2 = 0; kq2 < 2; ++kq2)
#pragma unroll
      for (int hh = 0; hh < 2; ++hh)
        load_lds16(Ksrc + (size_t)(hh * 16 + srow) * 3072 + kq2 * 32 + scol,
                   &Ks[kq2 * 4096 + (wave * 32 + hh * 16) * 32]);
    // stage V^T (coalesced read, scalar scatter writes: 2-way banks = free)
    const unsigned short* vrow = Vb + (size_t)(kb * 128 + vkey) * 3072 + vdd;
#pragma unroll
    for (int c = 0; c < 4; ++c) {
      short8 vv = *(const short8*)(vrow + c * 8);
#pragma unroll
      for (int e = 0; e < 8; ++e)
        vt[(vdd + c * 8 + e) * 136 + vkey] = (unsigned short)vv[e];
    }
    __syncthreads();

    const bool diag = (kb == qb);
    const int jhiA[2] = { diag ? 2 * wave : 7, diag ? 2 * wave + 1 : 7 };

    // S = Q K^T from LDS
    floatx4 s[2][8];
#pragma unroll
    for (int i = 0; i < 2; ++i)
#pragma unroll
      for (int j = 0; j < 8; ++j) s[i][j] = (floatx4){0.f, 0.f, 0.f, 0.f};
#pragma unroll
    for (int j = 0; j < 8; ++j) {
      if (j > jhiA[1]) continue;  // wave-uniform skip (fully masked)
      short8 kf0 = *(const short8*)&Ks[(16*j + frow) * 32 + fk];
      short8 kf1 = *(const short8*)&Ks[4096 + (16*j + frow) * 32 + fk];
#pragma unroll
      for (int i = 0; i < 2; ++i) {
        if (j > jhiA[i]) continue;
        s[i][j] = __builtin_amdgcn_mfma_f32_16x16x32_bf16(qf[i][0], kf0, s[i][j], 0, 0, 0);
        s[i][j] = __builtin_amdgcn_mfma_f32_16x16x32_bf16(qf[i][1], kf1, s[i][j], 0, 0, 0);
      }
    }
    // scale into log2 domain + causal mask
#pragma unroll
    for (int i = 0; i < 2; ++i) {
#pragma unroll
      for (int j = 0; j < 8; ++j) {
        if (j > jhiA[i]) continue;
#pragma unroll
        for (int r = 0; r < 4; ++r) {
          float v = s[i][j][r] * 0.1803368801f;  // 0.125 * log2(e)
          if (diag) {
            int qq = wave * 32 + 16*i + g4 + r;
            int kk = 16*j + frow;
            if (kk > qq) v = -1e30f;
          }
          s[i][j][r] = v;
        }
      }
    }
    // online softmax (base-2) per q-row; rows spread over 16 lanes
#pragma unroll
    for (int i = 0; i < 2; ++i) {
#pragma unroll
      for (int r = 0; r < 4; ++r) {
        float mx = -1e30f;
#pragma unroll
        for (int j = 0; j < 8; ++j) if (j <= jhiA[i]) mx = fmaxf(mx, s[i][j][r]);
        mx = fmaxf(mx, __shfl_xor(mx, 1));
        mx = fmaxf(mx, __shfl_xor(mx, 2));
        mx = fmaxf(mx, __shfl_xor(mx, 4));
        mx = fmaxf(mx, __shfl_xor(mx, 8));
        float mnew = fmaxf(m_s[i][r], mx);
        float alpha = exp2f(m_s[i][r] - mnew);
        m_s[i][r] = mnew;
        float rs = 0.f;
#pragma unroll
        for (int j = 0; j < 8; ++j) {
          if (j <= jhiA[i]) {
            float p = exp2f(s[i][j][r] - mnew);
            s[i][j][r] = p;
            rs += p;
          } else {
            s[i][j][r] = 0.f;
          }
        }
        rs += __shfl_xor(rs, 1);
        rs += __shfl_xor(rs, 2);
        rs += __shfl_xor(rs, 4);
        rs += __shfl_xor(rs, 8);
        l_s[i][r] = l_s[i][r] * alpha + rs;
#pragma unroll
        for (int jt = 0; jt < 4; ++jt) o[i][jt][r] *= alpha;
      }
    }
    // P -> LDS (wave-private region: no barrier needed, same-wave DS ordering)
    unsigned short* pw = pl + wave * 32 * 136;
#pragma unroll
    for (int i = 0; i < 2; ++i)
#pragma unroll
      for (int j = 0; j < 8; ++j)
#pragma unroll
        for (int r = 0; r < 4; ++r)
          pw[(16*i + g4 + r) * 136 + 16*j + frow] = f2b(s[i][j][r]);
    // PV (skip kk-chunks that are fully masked on the diagonal block)
    const int kkhi = diag ? wave : 3;
#pragma unroll
    for (int kk = 0; kk < 4; ++kk) {
      if (kk > kkhi) continue;
      short8 pa[2], vb2[4];
#pragma unroll
      for (int i = 0; i < 2; ++i)
        pa[i] = *(const short8*)&pl[(wave * 32 + 16*i + frow) * 136 + kk * 32 + fk];
#pragma unroll
      for (int jt = 0; jt < 4; ++jt)
        vb2[jt] = *(const short8*)&vt[(16*jt + frow) * 136 + kk * 32 + fk];
#pragma unroll
      for (int i = 0; i < 2; ++i)
#pragma unroll
        for (int jt = 0; jt < 4; ++jt)
          o[i][jt] = __builtin_amdgcn_mfma_f32_16x16x32_bf16(pa[i], vb2[jt], o[i][jt], 0, 0, 0);
    }
  }

  float inv[2][4];
#pragma unroll
  for (int i = 0; i < 2; ++i)
#pragma unroll
    for (int r = 0; r < 4; ++r) inv[i][r] = 1.0f / l_s[i][r];
#pragma unroll
  for (int i = 0; i < 2; ++i)
#pragma unroll
    for (int jt = 0; jt < 4; ++jt)
#pragma unroll
      for (int r = 0; r < 4; ++r) {
        int row = b * 2048 + qb * 128 + wave * 32 + 16*i + g4 + r;
        int col = h * 64 + 16*jt + frow;
        out[(size_t)row * 1024 + col] = f2b(o[i][jt][r] * inv[i][r]);
      }
}

// ---------------- launcher ----------------
extern "C" void kernel_launch(void* const* d_in, const int* in_sizes, int n_in,
                              void* d_out, int out_size, void* d_ws, size_t ws_size,
                              hipStream_t stream) {
  const float* x      = (const float*)d_in[0];   // [2,2048,1024]
  const float* w_qkv  = (const float*)d_in[1];   // [3072,1024]
  const float* w_o    = (const float*)d_in[2];   // [1024,1024]
  const float* w_up   = (const float*)d_in[3];   // [4096,1024]
  const float* w_gate = (const float*)d_in[4];   // [4096,1024]
  const float* w_down = (const float*)d_in[5];   // [1024,4096]
  const float* scale1 = (const float*)d_in[6];
  const float* scale2 = (const float*)d_in[7];

  char* ws = (char*)d_ws;
  unsigned short* wq_b = (unsigned short*)(ws);                 //  6,291,456 B
  unsigned short* wo_b = (unsigned short*)(ws +  6291456);      //  2,097,152 B
  unsigned short* wu_b = (unsigned short*)(ws +  8388608);      //  8,388,608 B
  unsigned short* wg_b = (unsigned short*)(ws + 16777216);      //  8,388,608 B
  unsigned short* wd_b = (unsigned short*)(ws + 25165824);      //  8,388,608 B
  unsigned short* qkv  = (unsigned short*)(ws + 33554432);      // 25,165,824 B (bf16)
  unsigned short* hup  = (unsigned short*)(ws + 33554432);      // 33,554,432 B (aliases qkv)
  unsigned short* xn   = (unsigned short*)(ws + 67108864);      //  8,388,608 B (bf16)
  unsigned short* attnb= (unsigned short*)(ws + 75497472);      //  8,388,608 B (bf16)
  float*          x1   = (float*)         (ws + 83886080);      // 16,777,216 B (fp32)
  float*          outp = (float*)d_out;                         // fp32

  const int M = 4096;
  dim3 blk(256);

  // weights fp32 -> bf16
  cvt_kernel<<<(3145728/4 + 255)/256, blk, 0, stream>>>(w_qkv,  wq_b, 3145728/4);
  cvt_kernel<<<(1048576/4 + 255)/256, blk, 0, stream>>>(w_o,    wo_b, 1048576/4);
  cvt_kernel<<<(4194304/4 + 255)/256, blk, 0, stream>>>(w_up,   wu_b, 4194304/4);
  cvt_kernel<<<(4194304/4 + 255)/256, blk, 0, stream>>>(w_gate, wg_b, 4194304/4);
  cvt_kernel<<<(4194304/4 + 255)/256, blk, 0, stream>>>(w_down, wd_b, 4194304/4);

  // x1 = x + W_o( attn( rms(x) ) )
  rmsnorm_kernel<<<4096, blk, 0, stream>>>(x, scale1, xn);
  gemm_bt<EPI_NONE, unsigned short, unsigned short>
      <<<dim3(24, 32), blk, 0, stream>>>(xn, wq_b, qkv, (const unsigned short*)nullptr, M, 3072, 1024);
  attn_kernel<<<dim3(512), blk, 0, stream>>>(qkv, attnb);
  gemm_bt<EPI_RES, float, float>
      <<<dim3(8, 32), blk, 0, stream>>>(attnb, wo_b, x1, x, M, 1024, 1024);

  // out = x1 + W_down( up(rms(x1)) * silu(gate(rms(x1))) )
  rmsnorm_kernel<<<4096, blk, 0, stream>>>(x1, scale2, xn);
  gemm_bt<EPI_NONE, unsigned short, unsigned short>
      <<<dim3(32, 32), blk, 0, stream>>>(xn, wu_b, hup, (const unsigned short*)nullptr, M, 4096, 1024);
  gemm_bt<EPI_GATE, unsigned short, unsigned short>
      <<<dim3(32, 32), blk, 0, stream>>>(xn, wg_b, hup, hup, M, 4096, 1024);
  gemm_bt<EPI_RES, float, float>
      <<<dim3(8, 32), blk, 0, stream>>>(hup, wd_b, outp, x1, M, 1024, 4096);

  (void)in_sizes; (void)n_in; (void)out_size; (void)ws_size;
}

// Round 4
// 552.635 us; speedup vs baseline: 1.0482x; 1.0192x over previous
//
#include <hip/hip_runtime.h>

// TransformerBlock: x = x + attn(rms(x)); x = x + mlp(rms(x))
// B=2, S=2048, D=1024, H=16, dh=64, EXP=4. Inputs/outputs fp32; internal bf16 MFMA.

typedef __attribute__((ext_vector_type(8))) short short8;   // 8 x bf16 = 4 VGPR
typedef __attribute__((ext_vector_type(4))) float floatx4;  // MFMA 16x16 acc

#define EPI_NONE 0
#define EPI_RES  1
#define EPI_GATE 2
#define EPI_QKV  3

#define QSCALE 0.1803368801f   // 0.125 * log2(e): folded into Q so softmax is base-2

__device__ __forceinline__ float b2f(unsigned short u) {
  union { unsigned int i; float f; } c; c.i = ((unsigned int)u) << 16; return c.f;
}
__device__ __forceinline__ unsigned short f2b(float f) {
  union { float f; unsigned int u; } c; c.f = f;
  unsigned int r = 0x7fffu + ((c.u >> 16) & 1u);
  return (unsigned short)((c.u + r) >> 16);
}
__device__ __forceinline__ unsigned int f2b2(float a, float b) {
  return (unsigned int)f2b(a) | ((unsigned int)f2b(b) << 16);
}

__device__ __forceinline__ void load_lds16(const void* g, void* l) {
  __builtin_amdgcn_global_load_lds(
      (const __attribute__((address_space(1))) unsigned int*)g,
      (__attribute__((address_space(3))) unsigned int*)l, 16, 0, 0);
}

// ---------------- fp32 -> bf16 convert (weights) ----------------
__global__ __launch_bounds__(256)
void cvt_kernel(const float* __restrict__ in, unsigned short* __restrict__ out, int n4) {
  int i = blockIdx.x * 256 + threadIdx.x;
  if (i >= n4) return;
  float4 v = ((const float4*)in)[i];
  ushort4 o;
  o.x = f2b(v.x); o.y = f2b(v.y); o.z = f2b(v.z); o.w = f2b(v.w);
  ((ushort4*)out)[i] = o;
}

// ---------------- RMSNorm: one block per row of 1024, fp32 in -> bf16 out ----------------
__global__ __launch_bounds__(256)
void rmsnorm_kernel(const float* __restrict__ x,
                    const float* __restrict__ scale,
                    unsigned short* __restrict__ y) {
  const int row = blockIdx.x;
  const int tid = threadIdx.x;
  const int base = row * 1024 + tid * 4;
  float4 v = *(const float4*)(x + base);
  float ss = v.x*v.x + v.y*v.y + v.z*v.z + v.w*v.w;
#pragma unroll
  for (int d = 32; d > 0; d >>= 1) ss += __shfl_down(ss, d);
  __shared__ float red[4];
  const int wave = tid >> 6, lane = tid & 63;
  if (lane == 0) red[wave] = ss;
  __syncthreads();
  float tot = red[0] + red[1] + red[2] + red[3];
  float rs = rsqrtf(tot * (1.0f/1024.0f) + 1e-6f);
  float4 sv = *(const float4*)(scale + tid * 4);
  ushort4 o;
  o.x = f2b(v.x * rs * sv.x);
  o.y = f2b(v.y * rs * sv.y);
  o.z = f2b(v.z * rs * sv.z);
  o.w = f2b(v.w * rs * sv.w);
  *(ushort4*)(y + base) = o;
}

// ---------------- GEMM: C[M,N] = A[M,K] @ B[N,K]^T (m97 structure) ----------------
template<int EPI, typename OutT, typename ResT>
__global__ __launch_bounds__(256)
void gemm_bt(const unsigned short* __restrict__ A,
             const unsigned short* __restrict__ B,
             OutT* C, const ResT* R, int M, int N, int K) {
  __shared__ __align__(16) unsigned short As[128 * 32];
  __shared__ __align__(16) unsigned short Bs[128 * 32];
  const int tid = threadIdx.x;
  const int wave = tid >> 6;
  const int lane = tid & 63;
  const int m0 = blockIdx.y * 128;
  const int n0 = blockIdx.x * 128;
  const int wm = (wave & 1) * 64;
  const int wn = (wave >> 1) * 64;
  const int frow = lane & 15;
  const int fk = (lane >> 4) * 8;

  floatx4 acc[4][4];
#pragma unroll
  for (int i = 0; i < 4; ++i)
#pragma unroll
    for (int j = 0; j < 4; ++j) acc[i][j] = (floatx4){0.f, 0.f, 0.f, 0.f};

  const int srow = lane >> 2;
  const int scol = (lane & 3) * 8;
  const unsigned short* Ag  = A + (size_t)(m0 + wave * 16 + srow) * K + scol;
  const unsigned short* Ag2 = A + (size_t)(m0 + (wave + 4) * 16 + srow) * K + scol;
  const unsigned short* Bg  = B + (size_t)(n0 + wave * 16 + srow) * K + scol;
  const unsigned short* Bg2 = B + (size_t)(n0 + (wave + 4) * 16 + srow) * K + scol;

  for (int k0 = 0; k0 < K; k0 += 32) {
    __syncthreads();
    load_lds16(Ag + k0,  &As[wave * 512]);
    load_lds16(Ag2 + k0, &As[(wave + 4) * 512]);
    load_lds16(Bg + k0,  &Bs[wave * 512]);
    load_lds16(Bg2 + k0, &Bs[(wave + 4) * 512]);
    __syncthreads();
    short8 af[4], bf[4];
#pragma unroll
    for (int i = 0; i < 4; ++i) af[i] = *(const short8*)&As[(wm + 16*i + frow)*32 + fk];
#pragma unroll
    for (int j = 0; j < 4; ++j) bf[j] = *(const short8*)&Bs[(wn + 16*j + frow)*32 + fk];
#pragma unroll
    for (int i = 0; i < 4; ++i)
#pragma unroll
      for (int j = 0; j < 4; ++j)
        acc[i][j] = __builtin_amdgcn_mfma_f32_16x16x32_bf16(af[i], bf[j], acc[i][j], 0, 0, 0);
  }

  const int g4 = (lane >> 4) * 4;
#pragma unroll
  for (int i = 0; i < 4; ++i) {
#pragma unroll
    for (int r = 0; r < 4; ++r) {
      const int row = m0 + wm + 16*i + g4 + r;
#pragma unroll
      for (int j = 0; j < 4; ++j) {
        const int col = n0 + wn + 16*j + frow;
        const size_t idx = (size_t)row * N + col;
        float v = acc[i][j][r];
        if constexpr (EPI == EPI_RES) {
          v += (float)R[idx];
        } else if constexpr (EPI == EPI_GATE) {
          float up = b2f((unsigned short)R[idx]);
          v = up * (v / (1.f + __expf(-v)));
        } else if constexpr (EPI == EPI_QKV) {
          if (col < 1024) v *= QSCALE;  // pre-scale Q for base-2 softmax
        }
        if constexpr (sizeof(OutT) == 4) C[idx] = v;
        else                             C[idx] = f2b(v);
      }
    }
  }
}

// ---------------- Flash attention (causal), dh=64, transposed-S form ----------------
// S^T = MFMA(A=K, B=Q): keys on registers, queries on lanes -> in-lane softmax.
// Block = 64 q-rows (4 waves x 16 q), K-tile = 128 keys.
// grid 1024 = 32 qblk x 32 bh; qblk swizzled so co-resident blocks balance.
__global__ __launch_bounds__(256, 4)
void attn_kernel(const unsigned short* __restrict__ qkv,  // [B*S, 3072] bf16 (Q pre-scaled)
                 unsigned short* __restrict__ out) {      // [B*S, 1024] bf16
  const int lin = blockIdx.x;
  const int bh = lin & 31;
  const int q_idx = lin >> 5;
  const int qblk = (q_idx < 16) ? (2 * q_idx) : (63 - 2 * q_idx);
  const int b = bh >> 4, h = bh & 15;
  const int tid = threadIdx.x, w = tid >> 6, lane = tid & 63;
  const int f = lane & 15, g = lane >> 4;
  const int fk = g * 8, g4 = g * 4;

  __shared__ __align__(16) unsigned short vt[64 * 136];   // V^T [d][key] pad 136 : 17408 B
  __shared__ __align__(16) unsigned int   pl[4 * 64 * 20];// P^T packed, per wave : 20480 B

  const unsigned short* Qb = qkv + (size_t)(b * 2048) * 3072 + h * 64;
  const unsigned short* Kb = Qb + 1024;
  const unsigned short* Vb = Qb + 2048;

  // Q as B-operand fragments (row=q on lanes, k=d on fk) — layout == A-frag layout
  const int qrow = qblk * 64 + w * 16 + f;
  const short8 qf0 = *(const short8*)(Qb + (size_t)qrow * 3072 + fk);
  const short8 qf1 = *(const short8*)(Qb + (size_t)qrow * 3072 + 32 + fk);

  float m_s = -1e30f, l_s = 0.f;
  floatx4 o[4];
#pragma unroll
  for (int mt = 0; mt < 4; ++mt) o[mt] = (floatx4){0.f, 0.f, 0.f, 0.f};

  const int vkey = tid & 127;
  const int vdd = (tid >> 7) * 32;
  const int kbmax = qblk >> 1;
  const int p = qblk & 1;
  unsigned int* plw = pl + w * (64 * 20);

  for (int kb = 0; kb <= kbmax; ++kb) {
    __syncthreads();  // prior iteration's vt reads done
    // stage V^T (coalesced 16B reads, u16 scatter: ~2-way banks)
    const unsigned short* vrow = Vb + (size_t)(kb * 128 + vkey) * 3072 + vdd;
#pragma unroll
    for (int c = 0; c < 4; ++c) {
      short8 vv = *(const short8*)(vrow + c * 8);
#pragma unroll
      for (int e = 0; e < 8; ++e)
        vt[(vdd + c * 8 + e) * 136 + vkey] = (unsigned short)vv[e];
    }
    __syncthreads();

    const bool diag = (kb == kbmax);
    const int jhi = diag ? (4 * p + w) : 7;   // wave-uniform causal tile bound

    // S^T = K·Q^T : K A-frags straight from global (L2-resident)
    floatx4 s[8];
#pragma unroll
    for (int j = 0; j < 8; ++j) {
      if (j > jhi) continue;
      s[j] = (floatx4){0.f, 0.f, 0.f, 0.f};
      const unsigned short* kp = Kb + (size_t)(kb * 128 + 16 * j + f) * 3072 + fk;
      short8 kf0 = *(const short8*)kp;
      short8 kf1 = *(const short8*)(kp + 32);
      s[j] = __builtin_amdgcn_mfma_f32_16x16x32_bf16(kf0, qf0, s[j], 0, 0, 0);
      s[j] = __builtin_amdgcn_mfma_f32_16x16x32_bf16(kf1, qf1, s[j], 0, 0, 0);
    }
    // causal mask (diag tile only): key_local = 16j+g4+r, q offset = 64p+16w+f
    if (diag) {
      const int qo = 64 * p + 16 * w + f;
#pragma unroll
      for (int j = 0; j < 8; ++j) {
        if (j > jhi) continue;
#pragma unroll
        for (int r = 0; r < 4; ++r)
          if (16 * j + g4 + r > qo) s[j][r] = -1e30f;
      }
    }
    // online softmax (base-2; scores pre-scaled): in-lane + 2 shuffles
    float mx = -1e30f;
#pragma unroll
    for (int j = 0; j < 8; ++j) {
      if (j > jhi) continue;
#pragma unroll
      for (int r = 0; r < 4; ++r) mx = fmaxf(mx, s[j][r]);
    }
    mx = fmaxf(mx, __shfl_xor(mx, 16));
    mx = fmaxf(mx, __shfl_xor(mx, 32));
    const float mnew = fmaxf(m_s, mx);
    const float alpha = exp2f(m_s - mnew);
    float rs = 0.f;
#pragma unroll
    for (int j = 0; j < 8; ++j) {
      if (j > jhi) continue;
#pragma unroll
      for (int r = 0; r < 4; ++r) {
        float pv = exp2f(s[j][r] - mnew);
        s[j][r] = pv;
        rs += pv;
      }
    }
    rs += __shfl_xor(rs, 16);
    rs += __shfl_xor(rs, 32);
    l_s = l_s * alpha + rs;
    m_s = mnew;
#pragma unroll
    for (int mt = 0; mt < 4; ++mt) o[mt] *= alpha;

    // P^T -> LDS, packed dwords (2 keys/dword), stride 20: 2-way-conflict-free
#pragma unroll
    for (int j = 0; j < 8; ++j) {
      if (j > jhi) continue;
      plw[(8 * j + 2 * g + 0) * 20 + f] = f2b2(s[j][0], s[j][1]);
      plw[(8 * j + 2 * g + 1) * 20 + f] = f2b2(s[j][2], s[j][3]);
    }
    if (diag && !(jhi & 1)) {  // zero the untouched tile inside the last PV chunk
      plw[(8 * (jhi + 1) + 2 * g + 0) * 20 + f] = 0u;
      plw[(8 * (jhi + 1) + 2 * g + 1) * 20 + f] = 0u;
    }

    // O^T += V^T · P : A = V^T frags from vt, B = P frags from plw (wave-private)
    const int chi = diag ? (jhi >> 1) : 3;
#pragma unroll
    for (int c = 0; c < 4; ++c) {
      if (c > chi) continue;
      union { unsigned int d[4]; short8 v; } pb;
#pragma unroll
      for (int k = 0; k < 4; ++k)
        pb.d[k] = plw[(16 * c + 4 * g + k) * 20 + f];
#pragma unroll
      for (int mt = 0; mt < 4; ++mt) {
        short8 va = *(const short8*)&vt[(16 * mt + f) * 136 + c * 32 + fk];
        o[mt] = __builtin_amdgcn_mfma_f32_16x16x32_bf16(va, pb.v, o[mt], 0, 0, 0);
      }
    }
  }

  // write O^T: lane (g,f): q = qrow, d = 16mt+4g+r -> 4 consecutive cols (ushort4)
  const float inv = 1.0f / l_s;
  unsigned short* orow = out + (size_t)(b * 2048 + qblk * 64 + w * 16 + f) * 1024 + h * 64;
#pragma unroll
  for (int mt = 0; mt < 4; ++mt) {
    ushort4 ov;
    ov.x = f2b(o[mt][0] * inv);
    ov.y = f2b(o[mt][1] * inv);
    ov.z = f2b(o[mt][2] * inv);
    ov.w = f2b(o[mt][3] * inv);
    *(ushort4*)(orow + 16 * mt + g4) = ov;
  }
}

// ---------------- launcher ----------------
extern "C" void kernel_launch(void* const* d_in, const int* in_sizes, int n_in,
                              void* d_out, int out_size, void* d_ws, size_t ws_size,
                              hipStream_t stream) {
  const float* x      = (const float*)d_in[0];   // [2,2048,1024]
  const float* w_qkv  = (const float*)d_in[1];   // [3072,1024]
  const float* w_o    = (const float*)d_in[2];   // [1024,1024]
  const float* w_up   = (const float*)d_in[3];   // [4096,1024]
  const float* w_gate = (const float*)d_in[4];   // [4096,1024]
  const float* w_down = (const float*)d_in[5];   // [1024,4096]
  const float* scale1 = (const float*)d_in[6];
  const float* scale2 = (const float*)d_in[7];

  char* ws = (char*)d_ws;
  unsigned short* wq_b = (unsigned short*)(ws);                 //  6,291,456 B
  unsigned short* wo_b = (unsigned short*)(ws +  6291456);      //  2,097,152 B
  unsigned short* wu_b = (unsigned short*)(ws +  8388608);      //  8,388,608 B
  unsigned short* wg_b = (unsigned short*)(ws + 16777216);      //  8,388,608 B
  unsigned short* wd_b = (unsigned short*)(ws + 25165824);      //  8,388,608 B
  unsigned short* qkv  = (unsigned short*)(ws + 33554432);      // 25,165,824 B (bf16)
  unsigned short* hup  = (unsigned short*)(ws + 33554432);      // 33,554,432 B (aliases qkv)
  unsigned short* xn   = (unsigned short*)(ws + 67108864);      //  8,388,608 B (bf16)
  unsigned short* attnb= (unsigned short*)(ws + 75497472);      //  8,388,608 B (bf16)
  float*          x1   = (float*)         (ws + 83886080);      // 16,777,216 B (fp32)
  float*          outp = (float*)d_out;                         // fp32

  const int M = 4096;
  dim3 blk(256);

  // weights fp32 -> bf16
  cvt_kernel<<<(3145728/4 + 255)/256, blk, 0, stream>>>(w_qkv,  wq_b, 3145728/4);
  cvt_kernel<<<(1048576/4 + 255)/256, blk, 0, stream>>>(w_o,    wo_b, 1048576/4);
  cvt_kernel<<<(4194304/4 + 255)/256, blk, 0, stream>>>(w_up,   wu_b, 4194304/4);
  cvt_kernel<<<(4194304/4 + 255)/256, blk, 0, stream>>>(w_gate, wg_b, 4194304/4);
  cvt_kernel<<<(4194304/4 + 255)/256, blk, 0, stream>>>(w_down, wd_b, 4194304/4);

  // x1 = x + W_o( attn( rms(x) ) )
  rmsnorm_kernel<<<4096, blk, 0, stream>>>(x, scale1, xn);
  gemm_bt<EPI_QKV, unsigned short, unsigned short>
      <<<dim3(24, 32), blk, 0, stream>>>(xn, wq_b, qkv, (const unsigned short*)nullptr, M, 3072, 1024);
  attn_kernel<<<dim3(1024), blk, 0, stream>>>(qkv, attnb);
  gemm_bt<EPI_RES, float, float>
      <<<dim3(8, 32), blk, 0, stream>>>(attnb, wo_b, x1, x, M, 1024, 1024);

  // out = x1 + W_down( up(rms(x1)) * silu(gate(rms(x1))) )
  rmsnorm_kernel<<<4096, blk, 0, stream>>>(x1, scale2, xn);
  gemm_bt<EPI_NONE, unsigned short, unsigned short>
      <<<dim3(32, 32), blk, 0, stream>>>(xn, wu_b, hup, (const unsigned short*)nullptr, M, 4096, 1024);
  gemm_bt<EPI_GATE, unsigned short, unsigned short>
      <<<dim3(32, 32), blk, 0, stream>>>(xn, wg_b, hup, hup, M, 4096, 1024);
  gemm_bt<EPI_RES, float, float>
      <<<dim3(8, 32), blk, 0, stream>>>(hup, wd_b, outp, x1, M, 1024, 4096);

  (void)in_sizes; (void)n_in; (void)out_size; (void)ws_size;
}

// Round 5
// 521.461 us; speedup vs baseline: 1.1109x; 1.0598x over previous
//
#include <hip/hip_runtime.h>

// TransformerBlock: x = x + attn(rms(x)); x = x + mlp(rms(x))
// B=2, S=2048, D=1024, H=16, dh=64, EXP=4. Inputs/outputs fp32; internal bf16 MFMA.

typedef __attribute__((ext_vector_type(8))) short short8;   // 8 x bf16 = 4 VGPR
typedef __attribute__((ext_vector_type(4))) float floatx4;  // MFMA 16x16 acc

#define EPI_NONE 0
#define EPI_RES  1
#define EPI_GATE 2
#define EPI_QKV  3

#define QSCALE 0.1803368801f   // 0.125 * log2(e): folded into Q so softmax is base-2

__device__ __forceinline__ float b2f(unsigned short u) {
  union { unsigned int i; float f; } c; c.i = ((unsigned int)u) << 16; return c.f;
}
__device__ __forceinline__ unsigned short f2b(float f) {
  union { float f; unsigned int u; } c; c.f = f;
  unsigned int r = 0x7fffu + ((c.u >> 16) & 1u);
  return (unsigned short)((c.u + r) >> 16);
}
__device__ __forceinline__ unsigned int f2b2(float a, float b) {
  return (unsigned int)f2b(a) | ((unsigned int)f2b(b) << 16);
}

__device__ __forceinline__ void load_lds16(const void* g, void* l) {
  __builtin_amdgcn_global_load_lds(
      (const __attribute__((address_space(1))) unsigned int*)g,
      (__attribute__((address_space(3))) unsigned int*)l, 16, 0, 0);
}

// ---------------- fp32 -> bf16 convert (weights) ----------------
__global__ __launch_bounds__(256)
void cvt_kernel(const float* __restrict__ in, unsigned short* __restrict__ out, int n4) {
  int i = blockIdx.x * 256 + threadIdx.x;
  if (i >= n4) return;
  float4 v = ((const float4*)in)[i];
  ushort4 o;
  o.x = f2b(v.x); o.y = f2b(v.y); o.z = f2b(v.z); o.w = f2b(v.w);
  ((ushort4*)out)[i] = o;
}

// ---------------- RMSNorm: one block per row of 1024, fp32 in -> bf16 out ----------------
__global__ __launch_bounds__(256)
void rmsnorm_kernel(const float* __restrict__ x,
                    const float* __restrict__ scale,
                    unsigned short* __restrict__ y) {
  const int row = blockIdx.x;
  const int tid = threadIdx.x;
  const int base = row * 1024 + tid * 4;
  float4 v = *(const float4*)(x + base);
  float ss = v.x*v.x + v.y*v.y + v.z*v.z + v.w*v.w;
#pragma unroll
  for (int d = 32; d > 0; d >>= 1) ss += __shfl_down(ss, d);
  __shared__ float red[4];
  const int wave = tid >> 6, lane = tid & 63;
  if (lane == 0) red[wave] = ss;
  __syncthreads();
  float tot = red[0] + red[1] + red[2] + red[3];
  float rs = rsqrtf(tot * (1.0f/1024.0f) + 1e-6f);
  float4 sv = *(const float4*)(scale + tid * 4);
  ushort4 o;
  o.x = f2b(v.x * rs * sv.x);
  o.y = f2b(v.y * rs * sv.y);
  o.z = f2b(v.z * rs * sv.z);
  o.w = f2b(v.w * rs * sv.w);
  *(ushort4*)(y + base) = o;
}

// ---------------- GEMM: C[M,ldc] = A[M,K] @ B[N,K]^T (m97 structure) ----------------
// EPI_QKV: Q cols (<1024) scaled by QSCALE; V cols (>=2048) redirected to VT[b,h,d][s].
template<int EPI, typename OutT, typename ResT>
__global__ __launch_bounds__(256)
void gemm_bt(const unsigned short* __restrict__ A,
             const unsigned short* __restrict__ B,
             OutT* C, const ResT* R, unsigned short* VT,
             int M, int N, int K, int ldc) {
  __shared__ __align__(16) unsigned short As[128 * 32];
  __shared__ __align__(16) unsigned short Bs[128 * 32];
  const int tid = threadIdx.x;
  const int wave = tid >> 6;
  const int lane = tid & 63;
  const int m0 = blockIdx.y * 128;
  const int n0 = blockIdx.x * 128;
  const int wm = (wave & 1) * 64;
  const int wn = (wave >> 1) * 64;
  const int frow = lane & 15;
  const int fk = (lane >> 4) * 8;

  floatx4 acc[4][4];
#pragma unroll
  for (int i = 0; i < 4; ++i)
#pragma unroll
    for (int j = 0; j < 4; ++j) acc[i][j] = (floatx4){0.f, 0.f, 0.f, 0.f};

  const int srow = lane >> 2;
  const int scol = (lane & 3) * 8;
  const unsigned short* Ag  = A + (size_t)(m0 + wave * 16 + srow) * K + scol;
  const unsigned short* Ag2 = A + (size_t)(m0 + (wave + 4) * 16 + srow) * K + scol;
  const unsigned short* Bg  = B + (size_t)(n0 + wave * 16 + srow) * K + scol;
  const unsigned short* Bg2 = B + (size_t)(n0 + (wave + 4) * 16 + srow) * K + scol;

  for (int k0 = 0; k0 < K; k0 += 32) {
    __syncthreads();
    load_lds16(Ag + k0,  &As[wave * 512]);
    load_lds16(Ag2 + k0, &As[(wave + 4) * 512]);
    load_lds16(Bg + k0,  &Bs[wave * 512]);
    load_lds16(Bg2 + k0, &Bs[(wave + 4) * 512]);
    __syncthreads();
    short8 af[4], bf[4];
#pragma unroll
    for (int i = 0; i < 4; ++i) af[i] = *(const short8*)&As[(wm + 16*i + frow)*32 + fk];
#pragma unroll
    for (int j = 0; j < 4; ++j) bf[j] = *(const short8*)&Bs[(wn + 16*j + frow)*32 + fk];
#pragma unroll
    for (int i = 0; i < 4; ++i)
#pragma unroll
      for (int j = 0; j < 4; ++j)
        acc[i][j] = __builtin_amdgcn_mfma_f32_16x16x32_bf16(af[i], bf[j], acc[i][j], 0, 0, 0);
  }

  const int g4 = (lane >> 4) * 4;

  if constexpr (EPI == EPI_QKV) {
    if (n0 >= 2048) {
      // V tile: store transposed into VT[(b*16+h)*64+dd][s]
#pragma unroll
      for (int i = 0; i < 4; ++i) {
        const int row0 = m0 + wm + 16*i + g4;     // token index (r=0)
        const int b = row0 >> 11, s0 = row0 & 2047;
#pragma unroll
        for (int j = 0; j < 4; ++j) {
          const int col = n0 + wn + 16*j + frow;  // 2048..3071
          const int dg = col - 2048;
          const int rowv = (b << 10) + dg;        // (b*16+h)*64+dd == b*1024+dg
          ushort4 ov;
          ov.x = f2b(acc[i][j][0]);
          ov.y = f2b(acc[i][j][1]);
          ov.z = f2b(acc[i][j][2]);
          ov.w = f2b(acc[i][j][3]);
          *(ushort4*)(VT + (size_t)rowv * 2048 + s0) = ov;
        }
      }
      return;
    }
  }

  const float qs = (EPI == EPI_QKV && n0 < 1024) ? QSCALE : 1.0f;
#pragma unroll
  for (int i = 0; i < 4; ++i) {
#pragma unroll
    for (int r = 0; r < 4; ++r) {
      const int row = m0 + wm + 16*i + g4 + r;
#pragma unroll
      for (int j = 0; j < 4; ++j) {
        const int col = n0 + wn + 16*j + frow;
        const size_t idx = (size_t)row * ldc + col;
        float v = acc[i][j][r];
        if constexpr (EPI == EPI_RES) {
          v += (float)R[idx];
        } else if constexpr (EPI == EPI_GATE) {
          float up = b2f((unsigned short)R[idx]);
          v = up * (v / (1.f + __expf(-v)));
        } else if constexpr (EPI == EPI_QKV) {
          v *= qs;
        }
        if constexpr (sizeof(OutT) == 4) C[idx] = v;
        else                             C[idx] = f2b(v);
      }
    }
  }
}

// ---------------- Fused up+gate GEMM: hup = up(x) * silu(gate(x)) ----------------
// Same 128x128 tile; two B operands, dual accumulators, silu*mul epilogue.
__global__ __launch_bounds__(256, 2)
void gemm_upgate(const unsigned short* __restrict__ A,
                 const unsigned short* __restrict__ Bu,
                 const unsigned short* __restrict__ Bg,
                 unsigned short* __restrict__ C, int M, int N, int K) {
  __shared__ __align__(16) unsigned short As[128 * 32];
  __shared__ __align__(16) unsigned short Bus[128 * 32];
  __shared__ __align__(16) unsigned short Bgs[128 * 32];
  const int tid = threadIdx.x;
  const int wave = tid >> 6;
  const int lane = tid & 63;
  const int m0 = blockIdx.y * 128;
  const int n0 = blockIdx.x * 128;
  const int wm = (wave & 1) * 64;
  const int wn = (wave >> 1) * 64;
  const int frow = lane & 15;
  const int fk = (lane >> 4) * 8;

  floatx4 au[4][4], ag[4][4];
#pragma unroll
  for (int i = 0; i < 4; ++i)
#pragma unroll
    for (int j = 0; j < 4; ++j) {
      au[i][j] = (floatx4){0.f, 0.f, 0.f, 0.f};
      ag[i][j] = (floatx4){0.f, 0.f, 0.f, 0.f};
    }

  const int srow = lane >> 2;
  const int scol = (lane & 3) * 8;
  const unsigned short* Ag1 = A  + (size_t)(m0 + wave * 16 + srow) * K + scol;
  const unsigned short* Ag2 = A  + (size_t)(m0 + (wave + 4) * 16 + srow) * K + scol;
  const unsigned short* Bu1 = Bu + (size_t)(n0 + wave * 16 + srow) * K + scol;
  const unsigned short* Bu2 = Bu + (size_t)(n0 + (wave + 4) * 16 + srow) * K + scol;
  const unsigned short* Bg1 = Bg + (size_t)(n0 + wave * 16 + srow) * K + scol;
  const unsigned short* Bg2 = Bg + (size_t)(n0 + (wave + 4) * 16 + srow) * K + scol;

  for (int k0 = 0; k0 < K; k0 += 32) {
    __syncthreads();
    load_lds16(Ag1 + k0, &As[wave * 512]);
    load_lds16(Ag2 + k0, &As[(wave + 4) * 512]);
    load_lds16(Bu1 + k0, &Bus[wave * 512]);
    load_lds16(Bu2 + k0, &Bus[(wave + 4) * 512]);
    load_lds16(Bg1 + k0, &Bgs[wave * 512]);
    load_lds16(Bg2 + k0, &Bgs[(wave + 4) * 512]);
    __syncthreads();
    short8 af[4], bu[4], bg[4];
#pragma unroll
    for (int i = 0; i < 4; ++i) af[i] = *(const short8*)&As[(wm + 16*i + frow)*32 + fk];
#pragma unroll
    for (int j = 0; j < 4; ++j) {
      bu[j] = *(const short8*)&Bus[(wn + 16*j + frow)*32 + fk];
      bg[j] = *(const short8*)&Bgs[(wn + 16*j + frow)*32 + fk];
    }
#pragma unroll
    for (int i = 0; i < 4; ++i)
#pragma unroll
      for (int j = 0; j < 4; ++j) {
        au[i][j] = __builtin_amdgcn_mfma_f32_16x16x32_bf16(af[i], bu[j], au[i][j], 0, 0, 0);
        ag[i][j] = __builtin_amdgcn_mfma_f32_16x16x32_bf16(af[i], bg[j], ag[i][j], 0, 0, 0);
      }
  }

  const int g4 = (lane >> 4) * 4;
#pragma unroll
  for (int i = 0; i < 4; ++i) {
#pragma unroll
    for (int r = 0; r < 4; ++r) {
      const int row = m0 + wm + 16*i + g4 + r;
#pragma unroll
      for (int j = 0; j < 4; ++j) {
        const int col = n0 + wn + 16*j + frow;
        float g = ag[i][j][r];
        float v = au[i][j][r] * (g / (1.f + __expf(-g)));
        C[(size_t)row * N + col] = f2b(v);
      }
    }
  }
}

// ---------------- Flash attention (causal), dh=64, transposed-S, barrier-free ----------------
// S^T = MFMA(A=K, B=Q): keys on regs, queries on lanes. V^T read directly from
// the VT buffer written by the qkv GEMM -> no LDS staging, no __syncthreads.
// Block = 64 q (4 waves x 16 q); grid 1024 = 32 qblk x 32 bh, qblk swizzled.
__global__ __launch_bounds__(256, 4)
void attn_kernel(const unsigned short* __restrict__ qkv,  // [B*S, 2048] bf16: Q(scaled),K
                 const unsigned short* __restrict__ vt,   // [B*1024, 2048] bf16: V^T
                 unsigned short* __restrict__ out) {      // [B*S, 1024] bf16
  const int lin = blockIdx.x;
  const int bh = lin & 31;
  const int q_idx = lin >> 5;
  const int qblk = (q_idx < 16) ? (2 * q_idx) : (63 - 2 * q_idx);
  const int b = bh >> 4, h = bh & 15;
  const int tid = threadIdx.x, w = tid >> 6, lane = tid & 63;
  const int f = lane & 15, g = lane >> 4;
  const int fk = g * 8, g4 = g * 4;

  __shared__ __align__(16) unsigned int pl[4 * 64 * 20];  // P^T packed, per wave: 20480 B

  const unsigned short* Qb = qkv + (size_t)(b * 2048) * 2048 + h * 64;
  const unsigned short* Kb = Qb + 1024;
  const unsigned short* Vt = vt + ((size_t)(b * 16 + h) * 64) * 2048;

  const int qrow = qblk * 64 + w * 16 + f;
  const short8 qf0 = *(const short8*)(Qb + (size_t)qrow * 2048 + fk);
  const short8 qf1 = *(const short8*)(Qb + (size_t)qrow * 2048 + 32 + fk);

  float m_s = -1e30f, l_s = 0.f;
  floatx4 o[4];
#pragma unroll
  for (int mt = 0; mt < 4; ++mt) o[mt] = (floatx4){0.f, 0.f, 0.f, 0.f};

  const int kbmax = qblk >> 1;
  const int p = qblk & 1;
  unsigned int* plw = pl + w * (64 * 20);

  for (int kb = 0; kb <= kbmax; ++kb) {
    const bool diag = (kb == kbmax);
    const int jhi = diag ? (4 * p + w) : 7;   // wave-uniform causal tile bound

    // S^T = K·Q^T : K A-frags straight from global (L2-resident)
    floatx4 s[8];
#pragma unroll
    for (int j = 0; j < 8; ++j) {
      if (j > jhi) continue;
      s[j] = (floatx4){0.f, 0.f, 0.f, 0.f};
      const unsigned short* kp = Kb + (size_t)(kb * 128 + 16 * j + f) * 2048 + fk;
      short8 kf0 = *(const short8*)kp;
      short8 kf1 = *(const short8*)(kp + 32);
      s[j] = __builtin_amdgcn_mfma_f32_16x16x32_bf16(kf0, qf0, s[j], 0, 0, 0);
      s[j] = __builtin_amdgcn_mfma_f32_16x16x32_bf16(kf1, qf1, s[j], 0, 0, 0);
    }
    // causal mask (diag tile only): key_local = 16j+g4+r, q offset = 64p+16w+f
    if (diag) {
      const int qo = 64 * p + 16 * w + f;
#pragma unroll
      for (int j = 0; j < 8; ++j) {
        if (j > jhi) continue;
#pragma unroll
        for (int r = 0; r < 4; ++r)
          if (16 * j + g4 + r > qo) s[j][r] = -1e30f;
      }
    }
    // online softmax (base-2; scores pre-scaled): in-lane + 2 shuffles
    float mx = -1e30f;
#pragma unroll
    for (int j = 0; j < 8; ++j) {
      if (j > jhi) continue;
#pragma unroll
      for (int r = 0; r < 4; ++r) mx = fmaxf(mx, s[j][r]);
    }
    mx = fmaxf(mx, __shfl_xor(mx, 16));
    mx = fmaxf(mx, __shfl_xor(mx, 32));
    const float mnew = fmaxf(m_s, mx);
    const float alpha = exp2f(m_s - mnew);
    float rs = 0.f;
#pragma unroll
    for (int j = 0; j < 8; ++j) {
      if (j > jhi) continue;
#pragma unroll
      for (int r = 0; r < 4; ++r) {
        float pv = exp2f(s[j][r] - mnew);
        s[j][r] = pv;
        rs += pv;
      }
    }
    rs += __shfl_xor(rs, 16);
    rs += __shfl_xor(rs, 32);
    l_s = l_s * alpha + rs;
    m_s = mnew;
#pragma unroll
    for (int mt = 0; mt < 4; ++mt) o[mt] *= alpha;

    // P^T -> wave-private LDS, packed dwords (2 keys/dword), stride 20 (2-way = free)
#pragma unroll
    for (int j = 0; j < 8; ++j) {
      if (j > jhi) continue;
      plw[(8 * j + 2 * g + 0) * 20 + f] = f2b2(s[j][0], s[j][1]);
      plw[(8 * j + 2 * g + 1) * 20 + f] = f2b2(s[j][2], s[j][3]);
    }
    if (diag && !(jhi & 1)) {  // zero the untouched j-tile inside the last PV chunk
      plw[(8 * (jhi + 1) + 2 * g + 0) * 20 + f] = 0u;
      plw[(8 * (jhi + 1) + 2 * g + 1) * 20 + f] = 0u;
    }

    // O^T += V^T · P : A = V^T frags direct from global, B = P frags (wave-private LDS)
    const int chi = diag ? (jhi >> 1) : 3;
#pragma unroll
    for (int c = 0; c < 4; ++c) {
      if (c > chi) continue;
      union { unsigned int d[4]; short8 v; } pb;
#pragma unroll
      for (int k = 0; k < 4; ++k)
        pb.d[k] = plw[(16 * c + 4 * g + k) * 20 + f];
#pragma unroll
      for (int mt = 0; mt < 4; ++mt) {
        short8 va = *(const short8*)(Vt + (size_t)(16 * mt + f) * 2048 + kb * 128 + 32 * c + fk);
        o[mt] = __builtin_amdgcn_mfma_f32_16x16x32_bf16(va, pb.v, o[mt], 0, 0, 0);
      }
    }
  }

  // write O^T: lane (g,f): q = qrow, d = 16mt+g4+r -> ushort4 per mt
  const float inv = 1.0f / l_s;
  unsigned short* orow = out + (size_t)(b * 2048 + qblk * 64 + w * 16 + f) * 1024 + h * 64;
#pragma unroll
  for (int mt = 0; mt < 4; ++mt) {
    ushort4 ov;
    ov.x = f2b(o[mt][0] * inv);
    ov.y = f2b(o[mt][1] * inv);
    ov.z = f2b(o[mt][2] * inv);
    ov.w = f2b(o[mt][3] * inv);
    *(ushort4*)(orow + 16 * mt + g4) = ov;
  }
}

// ---------------- launcher ----------------
extern "C" void kernel_launch(void* const* d_in, const int* in_sizes, int n_in,
                              void* d_out, int out_size, void* d_ws, size_t ws_size,
                              hipStream_t stream) {
  const float* x      = (const float*)d_in[0];   // [2,2048,1024]
  const float* w_qkv  = (const float*)d_in[1];   // [3072,1024]
  const float* w_o    = (const float*)d_in[2];   // [1024,1024]
  const float* w_up   = (const float*)d_in[3];   // [4096,1024]
  const float* w_gate = (const float*)d_in[4];   // [4096,1024]
  const float* w_down = (const float*)d_in[5];   // [1024,4096]
  const float* scale1 = (const float*)d_in[6];
  const float* scale2 = (const float*)d_in[7];

  char* ws = (char*)d_ws;
  unsigned short* wq_b = (unsigned short*)(ws);                 //  6,291,456 B
  unsigned short* wo_b = (unsigned short*)(ws +  6291456);      //  2,097,152 B
  unsigned short* wu_b = (unsigned short*)(ws +  8388608);      //  8,388,608 B
  unsigned short* wg_b = (unsigned short*)(ws + 16777216);      //  8,388,608 B
  unsigned short* wd_b = (unsigned short*)(ws + 25165824);      //  8,388,608 B
  unsigned short* qkv  = (unsigned short*)(ws + 33554432);      // 16,777,216 B (Q,K; ldc 2048)
  unsigned short* hup  = (unsigned short*)(ws + 33554432);      // 33,554,432 B (aliases qkv+vT+attnb)
  unsigned short* vT   = (unsigned short*)(ws + 50331648);      //  8,388,608 B (V^T)
  unsigned short* attnb= (unsigned short*)(ws + 58720256);      //  8,388,608 B
  unsigned short* xn   = (unsigned short*)(ws + 67108864);      //  8,388,608 B
  float*          x1   = (float*)         (ws + 75497472);      // 16,777,216 B (fp32)
  float*          outp = (float*)d_out;                         // fp32

  const int M = 4096;
  dim3 blk(256);

  // weights fp32 -> bf16
  cvt_kernel<<<(3145728/4 + 255)/256, blk, 0, stream>>>(w_qkv,  wq_b, 3145728/4);
  cvt_kernel<<<(1048576/4 + 255)/256, blk, 0, stream>>>(w_o,    wo_b, 1048576/4);
  cvt_kernel<<<(4194304/4 + 255)/256, blk, 0, stream>>>(w_up,   wu_b, 4194304/4);
  cvt_kernel<<<(4194304/4 + 255)/256, blk, 0, stream>>>(w_gate, wg_b, 4194304/4);
  cvt_kernel<<<(4194304/4 + 255)/256, blk, 0, stream>>>(w_down, wd_b, 4194304/4);

  // x1 = x + W_o( attn( rms(x) ) )
  rmsnorm_kernel<<<4096, blk, 0, stream>>>(x, scale1, xn);
  gemm_bt<EPI_QKV, unsigned short, unsigned short>
      <<<dim3(24, 32), blk, 0, stream>>>(xn, wq_b, qkv, (const unsigned short*)nullptr, vT,
                                         M, 3072, 1024, 2048);
  attn_kernel<<<dim3(1024), blk, 0, stream>>>(qkv, vT, attnb);
  gemm_bt<EPI_RES, float, float>
      <<<dim3(8, 32), blk, 0, stream>>>(attnb, wo_b, x1, x, (unsigned short*)nullptr,
                                        M, 1024, 1024, 1024);

  // out = x1 + W_down( up(rms(x1)) * silu(gate(rms(x1))) )
  rmsnorm_kernel<<<4096, blk, 0, stream>>>(x1, scale2, xn);
  gemm_upgate<<<dim3(32, 32), blk, 0, stream>>>(xn, wu_b, wg_b, hup, M, 4096, 1024);
  gemm_bt<EPI_RES, float, float>
      <<<dim3(8, 32), blk, 0, stream>>>(hup, wd_b, outp, x1, (unsigned short*)nullptr,
                                        M, 1024, 4096, 1024);

  (void)in_sizes; (void)n_in; (void)out_size; (void)ws_size;
}

// Round 6
// 461.913 us; speedup vs baseline: 1.2541x; 1.1289x over previous
//
#include <hip/hip_runtime.h>

// TransformerBlock: x = x + attn(rms(x)); x = x + mlp(rms(x))
// B=2, S=2048, D=1024, H=16, dh=64, EXP=4. Inputs/outputs fp32; internal bf16 MFMA.

typedef __attribute__((ext_vector_type(8))) short short8;   // 8 x bf16 = 4 VGPR
typedef __attribute__((ext_vector_type(4))) float floatx4;  // MFMA 16x16 acc

#define EPI_NONE 0
#define EPI_RES  1
#define EPI_GATE 2
#define EPI_QKV  3

#define QSCALE 0.1803368801f   // 0.125 * log2(e): folded into Q so softmax is base-2

__device__ __forceinline__ float b2f(unsigned short u) {
  union { unsigned int i; float f; } c; c.i = ((unsigned int)u) << 16; return c.f;
}
__device__ __forceinline__ unsigned short f2b(float f) {
  union { float f; unsigned int u; } c; c.f = f;
  unsigned int r = 0x7fffu + ((c.u >> 16) & 1u);
  return (unsigned short)((c.u + r) >> 16);
}
__device__ __forceinline__ unsigned int f2b2(float a, float b) {
  return (unsigned int)f2b(a) | ((unsigned int)f2b(b) << 16);
}

__device__ __forceinline__ void load_lds16(const void* g, void* l) {
  __builtin_amdgcn_global_load_lds(
      (const __attribute__((address_space(1))) unsigned int*)g,
      (__attribute__((address_space(3))) unsigned int*)l, 16, 0, 0);
}

// ---------------- fp32 -> bf16 convert (weights) ----------------
__global__ __launch_bounds__(256)
void cvt_kernel(const float* __restrict__ in, unsigned short* __restrict__ out, int n4) {
  int i = blockIdx.x * 256 + threadIdx.x;
  if (i >= n4) return;
  float4 v = ((const float4*)in)[i];
  ushort4 o;
  o.x = f2b(v.x); o.y = f2b(v.y); o.z = f2b(v.z); o.w = f2b(v.w);
  ((ushort4*)out)[i] = o;
}

// ---------------- RMSNorm: one block per row of 1024, fp32 in -> bf16 out ----------------
__global__ __launch_bounds__(256)
void rmsnorm_kernel(const float* __restrict__ x,
                    const float* __restrict__ scale,
                    unsigned short* __restrict__ y) {
  const int row = blockIdx.x;
  const int tid = threadIdx.x;
  const int base = row * 1024 + tid * 4;
  float4 v = *(const float4*)(x + base);
  float ss = v.x*v.x + v.y*v.y + v.z*v.z + v.w*v.w;
#pragma unroll
  for (int d = 32; d > 0; d >>= 1) ss += __shfl_down(ss, d);
  __shared__ float red[4];
  const int wave = tid >> 6, lane = tid & 63;
  if (lane == 0) red[wave] = ss;
  __syncthreads();
  float tot = red[0] + red[1] + red[2] + red[3];
  float rs = rsqrtf(tot * (1.0f/1024.0f) + 1e-6f);
  float4 sv = *(const float4*)(scale + tid * 4);
  ushort4 o;
  o.x = f2b(v.x * rs * sv.x);
  o.y = f2b(v.y * rs * sv.y);
  o.z = f2b(v.z * rs * sv.z);
  o.w = f2b(v.w * rs * sv.w);
  *(ushort4*)(y + base) = o;
}

// ---------------- GEMM: C[M,ldc] = A[M,K] @ B[N,K]^T (m97 structure) ----------------
// EPI_QKV: Q cols (<1024) scaled by QSCALE; V cols (>=2048) redirected to VT[b,h,d][s].
template<int EPI, typename OutT, typename ResT>
__global__ __launch_bounds__(256)
void gemm_bt(const unsigned short* __restrict__ A,
             const unsigned short* __restrict__ B,
             OutT* C, const ResT* R, unsigned short* VT,
             int M, int N, int K, int ldc) {
  __shared__ __align__(16) unsigned short As[128 * 32];
  __shared__ __align__(16) unsigned short Bs[128 * 32];
  const int tid = threadIdx.x;
  const int wave = tid >> 6;
  const int lane = tid & 63;
  const int m0 = blockIdx.y * 128;
  const int n0 = blockIdx.x * 128;
  const int wm = (wave & 1) * 64;
  const int wn = (wave >> 1) * 64;
  const int frow = lane & 15;
  const int fk = (lane >> 4) * 8;

  floatx4 acc[4][4];
#pragma unroll
  for (int i = 0; i < 4; ++i)
#pragma unroll
    for (int j = 0; j < 4; ++j) acc[i][j] = (floatx4){0.f, 0.f, 0.f, 0.f};

  const int srow = lane >> 2;
  const int scol = (lane & 3) * 8;
  const unsigned short* Ag  = A + (size_t)(m0 + wave * 16 + srow) * K + scol;
  const unsigned short* Ag2 = A + (size_t)(m0 + (wave + 4) * 16 + srow) * K + scol;
  const unsigned short* Bg  = B + (size_t)(n0 + wave * 16 + srow) * K + scol;
  const unsigned short* Bg2 = B + (size_t)(n0 + (wave + 4) * 16 + srow) * K + scol;

  for (int k0 = 0; k0 < K; k0 += 32) {
    __syncthreads();
    load_lds16(Ag + k0,  &As[wave * 512]);
    load_lds16(Ag2 + k0, &As[(wave + 4) * 512]);
    load_lds16(Bg + k0,  &Bs[wave * 512]);
    load_lds16(Bg2 + k0, &Bs[(wave + 4) * 512]);
    __syncthreads();
    short8 af[4], bf[4];
#pragma unroll
    for (int i = 0; i < 4; ++i) af[i] = *(const short8*)&As[(wm + 16*i + frow)*32 + fk];
#pragma unroll
    for (int j = 0; j < 4; ++j) bf[j] = *(const short8*)&Bs[(wn + 16*j + frow)*32 + fk];
#pragma unroll
    for (int i = 0; i < 4; ++i)
#pragma unroll
      for (int j = 0; j < 4; ++j)
        acc[i][j] = __builtin_amdgcn_mfma_f32_16x16x32_bf16(af[i], bf[j], acc[i][j], 0, 0, 0);
  }

  const int g4 = (lane >> 4) * 4;

  if constexpr (EPI == EPI_QKV) {
    if (n0 >= 2048) {
      // V tile: store transposed into VT[(b*16+h)*64+dd][s]
#pragma unroll
      for (int i = 0; i < 4; ++i) {
        const int row0 = m0 + wm + 16*i + g4;     // token index (r=0)
        const int b = row0 >> 11, s0 = row0 & 2047;
#pragma unroll
        for (int j = 0; j < 4; ++j) {
          const int col = n0 + wn + 16*j + frow;  // 2048..3071
          const int dg = col - 2048;
          const int rowv = (b << 10) + dg;        // (b*16+h)*64+dd == b*1024+dg
          ushort4 ov;
          ov.x = f2b(acc[i][j][0]);
          ov.y = f2b(acc[i][j][1]);
          ov.z = f2b(acc[i][j][2]);
          ov.w = f2b(acc[i][j][3]);
          *(ushort4*)(VT + (size_t)rowv * 2048 + s0) = ov;
        }
      }
      return;
    }
  }

  const float qs = (EPI == EPI_QKV && n0 < 1024) ? QSCALE : 1.0f;
#pragma unroll
  for (int i = 0; i < 4; ++i) {
#pragma unroll
    for (int r = 0; r < 4; ++r) {
      const int row = m0 + wm + 16*i + g4 + r;
#pragma unroll
      for (int j = 0; j < 4; ++j) {
        const int col = n0 + wn + 16*j + frow;
        const size_t idx = (size_t)row * ldc + col;
        float v = acc[i][j][r];
        if constexpr (EPI == EPI_RES) {
          v += (float)R[idx];
        } else if constexpr (EPI == EPI_GATE) {
          float up = b2f((unsigned short)R[idx]);
          v = up * (v / (1.f + __expf(-v)));
        } else if constexpr (EPI == EPI_QKV) {
          v *= qs;
        }
        if constexpr (sizeof(OutT) == 4) C[idx] = v;
        else                             C[idx] = f2b(v);
      }
    }
  }
}

// ---------------- Fused up+gate GEMM: hup = up(x) * silu(gate(x)) ----------------
__global__ __launch_bounds__(256, 2)
void gemm_upgate(const unsigned short* __restrict__ A,
                 const unsigned short* __restrict__ Bu,
                 const unsigned short* __restrict__ Bg,
                 unsigned short* __restrict__ C, int M, int N, int K) {
  __shared__ __align__(16) unsigned short As[128 * 32];
  __shared__ __align__(16) unsigned short Bus[128 * 32];
  __shared__ __align__(16) unsigned short Bgs[128 * 32];
  const int tid = threadIdx.x;
  const int wave = tid >> 6;
  const int lane = tid & 63;
  const int m0 = blockIdx.y * 128;
  const int n0 = blockIdx.x * 128;
  const int wm = (wave & 1) * 64;
  const int wn = (wave >> 1) * 64;
  const int frow = lane & 15;
  const int fk = (lane >> 4) * 8;

  floatx4 au[4][4], ag[4][4];
#pragma unroll
  for (int i = 0; i < 4; ++i)
#pragma unroll
    for (int j = 0; j < 4; ++j) {
      au[i][j] = (floatx4){0.f, 0.f, 0.f, 0.f};
      ag[i][j] = (floatx4){0.f, 0.f, 0.f, 0.f};
    }

  const int srow = lane >> 2;
  const int scol = (lane & 3) * 8;
  const unsigned short* Ag1 = A  + (size_t)(m0 + wave * 16 + srow) * K + scol;
  const unsigned short* Ag2 = A  + (size_t)(m0 + (wave + 4) * 16 + srow) * K + scol;
  const unsigned short* Bu1 = Bu + (size_t)(n0 + wave * 16 + srow) * K + scol;
  const unsigned short* Bu2 = Bu + (size_t)(n0 + (wave + 4) * 16 + srow) * K + scol;
  const unsigned short* Bg1 = Bg + (size_t)(n0 + wave * 16 + srow) * K + scol;
  const unsigned short* Bg2 = Bg + (size_t)(n0 + (wave + 4) * 16 + srow) * K + scol;

  for (int k0 = 0; k0 < K; k0 += 32) {
    __syncthreads();
    load_lds16(Ag1 + k0, &As[wave * 512]);
    load_lds16(Ag2 + k0, &As[(wave + 4) * 512]);
    load_lds16(Bu1 + k0, &Bus[wave * 512]);
    load_lds16(Bu2 + k0, &Bus[(wave + 4) * 512]);
    load_lds16(Bg1 + k0, &Bgs[wave * 512]);
    load_lds16(Bg2 + k0, &Bgs[(wave + 4) * 512]);
    __syncthreads();
    short8 af[4], bu[4], bg[4];
#pragma unroll
    for (int i = 0; i < 4; ++i) af[i] = *(const short8*)&As[(wm + 16*i + frow)*32 + fk];
#pragma unroll
    for (int j = 0; j < 4; ++j) {
      bu[j] = *(const short8*)&Bus[(wn + 16*j + frow)*32 + fk];
      bg[j] = *(const short8*)&Bgs[(wn + 16*j + frow)*32 + fk];
    }
#pragma unroll
    for (int i = 0; i < 4; ++i)
#pragma unroll
      for (int j = 0; j < 4; ++j) {
        au[i][j] = __builtin_amdgcn_mfma_f32_16x16x32_bf16(af[i], bu[j], au[i][j], 0, 0, 0);
        ag[i][j] = __builtin_amdgcn_mfma_f32_16x16x32_bf16(af[i], bg[j], ag[i][j], 0, 0, 0);
      }
  }

  const int g4 = (lane >> 4) * 4;
#pragma unroll
  for (int i = 0; i < 4; ++i) {
#pragma unroll
    for (int r = 0; r < 4; ++r) {
      const int row = m0 + wm + 16*i + g4 + r;
#pragma unroll
      for (int j = 0; j < 4; ++j) {
        const int col = n0 + wn + 16*j + frow;
        float g = ag[i][j][r];
        float v = au[i][j][r] * (g / (1.f + __expf(-g)));
        C[(size_t)row * N + col] = f2b(v);
      }
    }
  }
}

// ---------------- Flash attention (causal), dh=64, S^T form, LDS-staged ----------------
// Block = 128 q for one (b,h); 4 waves x 32 q. K-tile = 128 keys per iter.
// K and V^T staged via global_load_lds (m97 pattern); S^T = MFMA(A=K,B=Q) so
// softmax is in-lane + 2 shuffles; P round-trips wave-private LDS (stride 36,
// 2-way banks = free). grid 512 = 16 q_idx x 32 bh; qblk swizzled so the two
// co-resident blocks per CU sum to a constant 17 iterations.
__global__ __launch_bounds__(256, 2)
void attn_kernel(const unsigned short* __restrict__ qkv,  // [B*S, 2048] bf16: Q(scaled),K
                 const unsigned short* __restrict__ vt,   // [B*1024, 2048] bf16: V^T
                 unsigned short* __restrict__ out) {      // [B*S, 1024] bf16
  const int lin = blockIdx.x;
  const int bh = lin & 31;
  const int q_idx = lin >> 5;                        // 0..15
  const int qblk = (q_idx < 8) ? (2 * q_idx) : (31 - 2 * q_idx);
  const int b = bh >> 4, h = bh & 15;
  const int tid = threadIdx.x, w = tid >> 6, lane = tid & 63;
  const int f = lane & 15, g = lane >> 4;
  const int fk = g * 8, g4 = g * 4;

  __shared__ __align__(16) unsigned short Ks[2][128 * 32];  // [kq][key][32]: 16 KB
  __shared__ __align__(16) unsigned short Vs[4][64 * 32];   // [c][d][32]:    16 KB
  __shared__ __align__(16) unsigned int   pl[4][64 * 36];   // per-wave P^T:  36 KB

  const unsigned short* Qb = qkv + (size_t)(b * 2048) * 2048 + h * 64;
  const unsigned short* Kb = Qb + 1024;
  const unsigned short* Vt = vt + ((size_t)(b * 16 + h) * 64) * 2048;

  // Q as B-operand frags: q = q0 + 16i + f, k = kq*32 + fk
  const int q0 = qblk * 128 + w * 32;
  short8 qf[2][2];
#pragma unroll
  for (int i = 0; i < 2; ++i)
#pragma unroll
    for (int kq = 0; kq < 2; ++kq)
      qf[i][kq] = *(const short8*)(Qb + (size_t)(q0 + 16*i + f) * 2048 + kq * 32 + fk);

  float m_s[2] = {-1e30f, -1e30f}, l_s[2] = {0.f, 0.f};
  floatx4 o[4][2];
#pragma unroll
  for (int mt = 0; mt < 4; ++mt)
#pragma unroll
    for (int i = 0; i < 2; ++i) o[mt][i] = (floatx4){0.f, 0.f, 0.f, 0.f};

  // staging lane roles: 16 keys/d per issue, lane l -> row l>>2, col (l&3)*8
  const int srow = lane >> 2;
  const int scol = (lane & 3) * 8;
  unsigned int* plw = pl[w];

  for (int kb = 0; kb <= qblk; ++kb) {
    __syncthreads();  // prior iteration's LDS reads complete
    // K: issues t = {w, w+4, w+8, w+12}: kq = t>>3, seg = t&7 (16 keys each)
#pragma unroll
    for (int u = 0; u < 2; ++u) {
      const int seg = w + 4 * u;
#pragma unroll
      for (int kq = 0; kq < 2; ++kq)
        load_lds16(Kb + (size_t)(kb * 128 + seg * 16 + srow) * 2048 + kq * 32 + scol,
                   &Ks[kq][seg * 512]);
    }
    // V: wave w stages d in [16w,16w+16) for all 4 key-chunks
#pragma unroll
    for (int c = 0; c < 4; ++c)
      load_lds16(Vt + (size_t)(w * 16 + srow) * 2048 + kb * 128 + c * 32 + scol,
                 &Vs[c][w * 512]);
    __syncthreads();  // drains vmcnt -> staging visible

    const bool diag = (kb == qblk);
    const int jhi0 = diag ? 2 * w : 7;       // causal tile bound, q-half 0
    const int jhi1 = diag ? 2 * w + 1 : 7;   // q-half 1

    // S^T = K . Q^T (K A-frags from LDS)
    floatx4 s[8][2];
#pragma unroll
    for (int j = 0; j < 8; ++j) {
      if (j > jhi1) continue;
      short8 kf0 = *(const short8*)&Ks[0][(16*j + f) * 32 + fk];
      short8 kf1 = *(const short8*)&Ks[1][(16*j + f) * 32 + fk];
#pragma unroll
      for (int i = 0; i < 2; ++i) {
        if (j > (i ? jhi1 : jhi0)) continue;
        s[j][i] = (floatx4){0.f, 0.f, 0.f, 0.f};
        s[j][i] = __builtin_amdgcn_mfma_f32_16x16x32_bf16(kf0, qf[i][0], s[j][i], 0, 0, 0);
        s[j][i] = __builtin_amdgcn_mfma_f32_16x16x32_bf16(kf1, qf[i][1], s[j][i], 0, 0, 0);
      }
    }
    // causal mask on diagonal tile: key_local = 16j+g4+r vs q_local = 32w+16i+f
    if (diag) {
#pragma unroll
      for (int i = 0; i < 2; ++i) {
        const int qo = 32 * w + 16 * i + f;
        const int jh = i ? jhi1 : jhi0;
#pragma unroll
        for (int j = 0; j < 8; ++j) {
          if (j > jh) continue;
#pragma unroll
          for (int r = 0; r < 4; ++r)
            if (16 * j + g4 + r > qo) s[j][i][r] = -1e30f;
        }
      }
    }
    // online softmax (base-2, scores pre-scaled): in-lane + 2 shuffles per half
#pragma unroll
    for (int i = 0; i < 2; ++i) {
      const int jh = i ? jhi1 : jhi0;
      float mx = -1e30f;
#pragma unroll
      for (int j = 0; j < 8; ++j) {
        if (j > jh) continue;
#pragma unroll
        for (int r = 0; r < 4; ++r) mx = fmaxf(mx, s[j][i][r]);
      }
      mx = fmaxf(mx, __shfl_xor(mx, 16));
      mx = fmaxf(mx, __shfl_xor(mx, 32));
      const float mnew = fmaxf(m_s[i], mx);
      const float alpha = exp2f(m_s[i] - mnew);
      float rs = 0.f;
#pragma unroll
      for (int j = 0; j < 8; ++j) {
        if (j > jh) continue;
#pragma unroll
        for (int r = 0; r < 4; ++r) {
          float pv = exp2f(s[j][i][r] - mnew);
          s[j][i][r] = pv;
          rs += pv;
        }
      }
      rs += __shfl_xor(rs, 16);
      rs += __shfl_xor(rs, 32);
      l_s[i] = l_s[i] * alpha + rs;
      m_s[i] = mnew;
#pragma unroll
      for (int mt = 0; mt < 4; ++mt) o[mt][i] *= alpha;
    }
    // P^T -> wave-private LDS: row = key/2 (stride 36 dwords), col = 16i+f
#pragma unroll
    for (int i = 0; i < 2; ++i) {
      const int jh = i ? jhi1 : jhi0;
#pragma unroll
      for (int j = 0; j < 8; ++j) {
        if (j > jh) continue;
        plw[(8*j + 2*g + 0) * 36 + 16*i + f] = f2b2(s[j][i][0], s[j][i][1]);
        plw[(8*j + 2*g + 1) * 36 + 16*i + f] = f2b2(s[j][i][2], s[j][i][3]);
      }
    }
    if (diag) {  // half 0 leaves tile j=2w+1 stale inside PV chunk w: zero its cols
      plw[(8*(2*w + 1) + 2*g + 0) * 36 + f] = 0u;
      plw[(8*(2*w + 1) + 2*g + 1) * 36 + f] = 0u;
    }
    // O^T += V^T . P : A = V^T frags (LDS), B = P frags (wave-private LDS)
    const int chi = diag ? w : 3;
#pragma unroll
    for (int c = 0; c < 4; ++c) {
      if (c > chi) continue;
      union { unsigned int d[4]; short8 v; } pb[2];
#pragma unroll
      for (int i = 0; i < 2; ++i)
#pragma unroll
        for (int k = 0; k < 4; ++k)
          pb[i].d[k] = plw[(16*c + 4*g + k) * 36 + 16*i + f];
#pragma unroll
      for (int mt = 0; mt < 4; ++mt) {
        short8 va = *(const short8*)&Vs[c][(16*mt + f) * 32 + fk];
#pragma unroll
        for (int i = 0; i < 2; ++i)
          o[mt][i] = __builtin_amdgcn_mfma_f32_16x16x32_bf16(va, pb[i].v, o[mt][i], 0, 0, 0);
      }
    }
  }

  // write O^T: q = q0+16i+f, d = 16mt+g4+r -> ushort4 per (mt,i)
#pragma unroll
  for (int i = 0; i < 2; ++i) {
    const float inv = 1.0f / l_s[i];
    unsigned short* orow = out + (size_t)(b * 2048 + q0 + 16*i + f) * 1024 + h * 64;
#pragma unroll
    for (int mt = 0; mt < 4; ++mt) {
      ushort4 ov;
      ov.x = f2b(o[mt][i][0] * inv);
      ov.y = f2b(o[mt][i][1] * inv);
      ov.z = f2b(o[mt][i][2] * inv);
      ov.w = f2b(o[mt][i][3] * inv);
      *(ushort4*)(orow + 16 * mt + g4) = ov;
    }
  }
}

// ---------------- launcher ----------------
extern "C" void kernel_launch(void* const* d_in, const int* in_sizes, int n_in,
                              void* d_out, int out_size, void* d_ws, size_t ws_size,
                              hipStream_t stream) {
  const float* x      = (const float*)d_in[0];   // [2,2048,1024]
  const float* w_qkv  = (const float*)d_in[1];   // [3072,1024]
  const float* w_o    = (const float*)d_in[2];   // [1024,1024]
  const float* w_up   = (const float*)d_in[3];   // [4096,1024]
  const float* w_gate = (const float*)d_in[4];   // [4096,1024]
  const float* w_down = (const float*)d_in[5];   // [1024,4096]
  const float* scale1 = (const float*)d_in[6];
  const float* scale2 = (const float*)d_in[7];

  char* ws = (char*)d_ws;
  unsigned short* wq_b = (unsigned short*)(ws);                 //  6,291,456 B
  unsigned short* wo_b = (unsigned short*)(ws +  6291456);      //  2,097,152 B
  unsigned short* wu_b = (unsigned short*)(ws +  8388608);      //  8,388,608 B
  unsigned short* wg_b = (unsigned short*)(ws + 16777216);      //  8,388,608 B
  unsigned short* wd_b = (unsigned short*)(ws + 25165824);      //  8,388,608 B
  unsigned short* qkv  = (unsigned short*)(ws + 33554432);      // 16,777,216 B (Q,K; ldc 2048)
  unsigned short* hup  = (unsigned short*)(ws + 33554432);      // 33,554,432 B (aliases qkv+vT+attnb)
  unsigned short* vT   = (unsigned short*)(ws + 50331648);      //  8,388,608 B (V^T)
  unsigned short* attnb= (unsigned short*)(ws + 58720256);      //  8,388,608 B
  unsigned short* xn   = (unsigned short*)(ws + 67108864);      //  8,388,608 B
  float*          x1   = (float*)         (ws + 75497472);      // 16,777,216 B (fp32)
  float*          outp = (float*)d_out;                         // fp32

  const int M = 4096;
  dim3 blk(256);

  // weights fp32 -> bf16
  cvt_kernel<<<(3145728/4 + 255)/256, blk, 0, stream>>>(w_qkv,  wq_b, 3145728/4);
  cvt_kernel<<<(1048576/4 + 255)/256, blk, 0, stream>>>(w_o,    wo_b, 1048576/4);
  cvt_kernel<<<(4194304/4 + 255)/256, blk, 0, stream>>>(w_up,   wu_b, 4194304/4);
  cvt_kernel<<<(4194304/4 + 255)/256, blk, 0, stream>>>(w_gate, wg_b, 4194304/4);
  cvt_kernel<<<(4194304/4 + 255)/256, blk, 0, stream>>>(w_down, wd_b, 4194304/4);

  // x1 = x + W_o( attn( rms(x) ) )
  rmsnorm_kernel<<<4096, blk, 0, stream>>>(x, scale1, xn);
  gemm_bt<EPI_QKV, unsigned short, unsigned short>
      <<<dim3(24, 32), blk, 0, stream>>>(xn, wq_b, qkv, (const unsigned short*)nullptr, vT,
                                         M, 3072, 1024, 2048);
  attn_kernel<<<dim3(512), blk, 0, stream>>>(qkv, vT, attnb);
  gemm_bt<EPI_RES, float, float>
      <<<dim3(8, 32), blk, 0, stream>>>(attnb, wo_b, x1, x, (unsigned short*)nullptr,
                                        M, 1024, 1024, 1024);

  // out = x1 + W_down( up(rms(x1)) * silu(gate(rms(x1))) )
  rmsnorm_kernel<<<4096, blk, 0, stream>>>(x1, scale2, xn);
  gemm_upgate<<<dim3(32, 32), blk, 0, stream>>>(xn, wu_b, wg_b, hup, M, 4096, 1024);
  gemm_bt<EPI_RES, float, float>
      <<<dim3(8, 32), blk, 0, stream>>>(hup, wd_b, outp, x1, (unsigned short*)nullptr,
                                        M, 1024, 4096, 1024);

  (void)in_sizes; (void)n_in; (void)out_size; (void)ws_size;
}

// Round 7
// 415.140 us; speedup vs baseline: 1.3954x; 1.1127x over previous
//
#include <hip/hip_runtime.h>

// TransformerBlock: x = x + attn(rms(x)); x = x + mlp(rms(x))
// B=2, S=2048, D=1024, H=16, dh=64, EXP=4. Inputs/outputs fp32; internal bf16 MFMA.

typedef __attribute__((ext_vector_type(8))) short short8;   // 8 x bf16 = 4 VGPR
typedef __attribute__((ext_vector_type(4))) float floatx4;  // MFMA 16x16 acc

#define EPI_NONE 0
#define EPI_RES  1
#define EPI_GATE 2
#define EPI_QKV  3

#define QSCALE 0.1803368801f   // 0.125 * log2(e): folded into Q so softmax is base-2

__device__ __forceinline__ float b2f(unsigned short u) {
  union { unsigned int i; float f; } c; c.i = ((unsigned int)u) << 16; return c.f;
}
__device__ __forceinline__ unsigned short f2b(float f) {
  union { float f; unsigned int u; } c; c.f = f;
  unsigned int r = 0x7fffu + ((c.u >> 16) & 1u);
  return (unsigned short)((c.u + r) >> 16);
}
__device__ __forceinline__ unsigned int f2b2(float a, float b) {
  return (unsigned int)f2b(a) | ((unsigned int)f2b(b) << 16);
}

__device__ __forceinline__ void load_lds16(const void* g, void* l) {
  __builtin_amdgcn_global_load_lds(
      (const __attribute__((address_space(1))) unsigned int*)g,
      (__attribute__((address_space(3))) unsigned int*)l, 16, 0, 0);
}

// ---------------- fused fp32 -> bf16 convert of all 5 weights ----------------
// float4 units: wq 786432, wo 262144, wu/wg/wd 1048576 each; total 4194304.
__global__ __launch_bounds__(256)
void cvt_all_kernel(const float* __restrict__ wq, const float* __restrict__ wo,
                    const float* __restrict__ wu, const float* __restrict__ wg,
                    const float* __restrict__ wd,
                    unsigned short* __restrict__ oq, unsigned short* __restrict__ oo,
                    unsigned short* __restrict__ ou, unsigned short* __restrict__ og,
                    unsigned short* __restrict__ od) {
  int i = blockIdx.x * 256 + threadIdx.x;
  const float* src; unsigned short* dst; int k;
  if (i < 786432)        { src = wq; dst = oq; k = i; }
  else if (i < 1048576)  { src = wo; dst = oo; k = i - 786432; }
  else if (i < 2097152)  { src = wu; dst = ou; k = i - 1048576; }
  else if (i < 3145728)  { src = wg; dst = og; k = i - 2097152; }
  else                   { src = wd; dst = od; k = i - 3145728; }
  float4 v = ((const float4*)src)[k];
  ushort4 o;
  o.x = f2b(v.x); o.y = f2b(v.y); o.z = f2b(v.z); o.w = f2b(v.w);
  ((ushort4*)dst)[k] = o;
}

// ---------------- RMSNorm: one block per row of 1024, fp32 in -> bf16 out ----------------
__global__ __launch_bounds__(256)
void rmsnorm_kernel(const float* __restrict__ x,
                    const float* __restrict__ scale,
                    unsigned short* __restrict__ y) {
  const int row = blockIdx.x;
  const int tid = threadIdx.x;
  const int base = row * 1024 + tid * 4;
  float4 v = *(const float4*)(x + base);
  float ss = v.x*v.x + v.y*v.y + v.z*v.z + v.w*v.w;
#pragma unroll
  for (int d = 32; d > 0; d >>= 1) ss += __shfl_down(ss, d);
  __shared__ float red[4];
  const int wave = tid >> 6, lane = tid & 63;
  if (lane == 0) red[wave] = ss;
  __syncthreads();
  float tot = red[0] + red[1] + red[2] + red[3];
  float rs = rsqrtf(tot * (1.0f/1024.0f) + 1e-6f);
  float4 sv = *(const float4*)(scale + tid * 4);
  ushort4 o;
  o.x = f2b(v.x * rs * sv.x);
  o.y = f2b(v.y * rs * sv.y);
  o.z = f2b(v.z * rs * sv.z);
  o.w = f2b(v.w * rs * sv.w);
  *(ushort4*)(y + base) = o;
}

// ---------------- RMSNorm + residual reduce: x1 = x + p0 + p1; y = rms(x1) ----------------
__global__ __launch_bounds__(256)
void rmsnorm_res2_kernel(const float* __restrict__ x,
                         const float* __restrict__ p0,
                         const float* __restrict__ p1,
                         const float* __restrict__ scale,
                         float* __restrict__ x1,
                         unsigned short* __restrict__ y) {
  const int row = blockIdx.x;
  const int tid = threadIdx.x;
  const int base = row * 1024 + tid * 4;
  float4 a = *(const float4*)(x + base);
  float4 b = *(const float4*)(p0 + base);
  float4 c = *(const float4*)(p1 + base);
  float4 v;
  v.x = a.x + b.x + c.x; v.y = a.y + b.y + c.y;
  v.z = a.z + b.z + c.z; v.w = a.w + b.w + c.w;
  *(float4*)(x1 + base) = v;
  float ss = v.x*v.x + v.y*v.y + v.z*v.z + v.w*v.w;
#pragma unroll
  for (int d = 32; d > 0; d >>= 1) ss += __shfl_down(ss, d);
  __shared__ float red[4];
  const int wave = tid >> 6, lane = tid & 63;
  if (lane == 0) red[wave] = ss;
  __syncthreads();
  float tot = red[0] + red[1] + red[2] + red[3];
  float rs = rsqrtf(tot * (1.0f/1024.0f) + 1e-6f);
  float4 sv = *(const float4*)(scale + tid * 4);
  ushort4 o;
  o.x = f2b(v.x * rs * sv.x);
  o.y = f2b(v.y * rs * sv.y);
  o.z = f2b(v.z * rs * sv.z);
  o.w = f2b(v.w * rs * sv.w);
  *(ushort4*)(y + base) = o;
}

// ---------------- final reduce: outp = x1 + outp + p1 (outp holds slice-0 partial) ----------------
__global__ __launch_bounds__(256)
void reduce_out_kernel(const float* __restrict__ x1,
                       const float* __restrict__ p1,
                       float* outp) {
  int i = blockIdx.x * 256 + threadIdx.x;
  float4 a = ((const float4*)x1)[i];
  float4 b = ((const float4*)p1)[i];
  float4 c = ((float4*)outp)[i];
  float4 v;
  v.x = a.x + b.x + c.x; v.y = a.y + b.y + c.y;
  v.z = a.z + b.z + c.z; v.w = a.w + b.w + c.w;
  ((float4*)outp)[i] = v;
}

// ---------------- GEMM: C[M,ldc] = A[M,K] @ B[N,K]^T (m97 structure) ----------------
// EPI_QKV: Q cols (<1024) scaled by QSCALE; V cols (>=2048) redirected to VT[b,h,d][s].
template<int EPI, typename OutT, typename ResT>
__global__ __launch_bounds__(256)
void gemm_bt(const unsigned short* __restrict__ A,
             const unsigned short* __restrict__ B,
             OutT* C, const ResT* R, unsigned short* VT,
             int M, int N, int K, int ldc) {
  __shared__ __align__(16) unsigned short As[128 * 32];
  __shared__ __align__(16) unsigned short Bs[128 * 32];
  const int tid = threadIdx.x;
  const int wave = tid >> 6;
  const int lane = tid & 63;
  const int m0 = blockIdx.y * 128;
  const int n0 = blockIdx.x * 128;
  const int wm = (wave & 1) * 64;
  const int wn = (wave >> 1) * 64;
  const int frow = lane & 15;
  const int fk = (lane >> 4) * 8;

  floatx4 acc[4][4];
#pragma unroll
  for (int i = 0; i < 4; ++i)
#pragma unroll
    for (int j = 0; j < 4; ++j) acc[i][j] = (floatx4){0.f, 0.f, 0.f, 0.f};

  const int srow = lane >> 2;
  const int scol = (lane & 3) * 8;
  const unsigned short* Ag  = A + (size_t)(m0 + wave * 16 + srow) * K + scol;
  const unsigned short* Ag2 = A + (size_t)(m0 + (wave + 4) * 16 + srow) * K + scol;
  const unsigned short* Bg  = B + (size_t)(n0 + wave * 16 + srow) * K + scol;
  const unsigned short* Bg2 = B + (size_t)(n0 + (wave + 4) * 16 + srow) * K + scol;

  for (int k0 = 0; k0 < K; k0 += 32) {
    __syncthreads();
    load_lds16(Ag + k0,  &As[wave * 512]);
    load_lds16(Ag2 + k0, &As[(wave + 4) * 512]);
    load_lds16(Bg + k0,  &Bs[wave * 512]);
    load_lds16(Bg2 + k0, &Bs[(wave + 4) * 512]);
    __syncthreads();
    short8 af[4], bf[4];
#pragma unroll
    for (int i = 0; i < 4; ++i) af[i] = *(const short8*)&As[(wm + 16*i + frow)*32 + fk];
#pragma unroll
    for (int j = 0; j < 4; ++j) bf[j] = *(const short8*)&Bs[(wn + 16*j + frow)*32 + fk];
#pragma unroll
    for (int i = 0; i < 4; ++i)
#pragma unroll
      for (int j = 0; j < 4; ++j)
        acc[i][j] = __builtin_amdgcn_mfma_f32_16x16x32_bf16(af[i], bf[j], acc[i][j], 0, 0, 0);
  }

  const int g4 = (lane >> 4) * 4;

  if constexpr (EPI == EPI_QKV) {
    if (n0 >= 2048) {
      // V tile: store transposed into VT[(b*16+h)*64+dd][s]
#pragma unroll
      for (int i = 0; i < 4; ++i) {
        const int row0 = m0 + wm + 16*i + g4;     // token index (r=0)
        const int b = row0 >> 11, s0 = row0 & 2047;
#pragma unroll
        for (int j = 0; j < 4; ++j) {
          const int col = n0 + wn + 16*j + frow;  // 2048..3071
          const int dg = col - 2048;
          const int rowv = (b << 10) + dg;        // (b*16+h)*64+dd == b*1024+dg
          ushort4 ov;
          ov.x = f2b(acc[i][j][0]);
          ov.y = f2b(acc[i][j][1]);
          ov.z = f2b(acc[i][j][2]);
          ov.w = f2b(acc[i][j][3]);
          *(ushort4*)(VT + (size_t)rowv * 2048 + s0) = ov;
        }
      }
      return;
    }
  }

  const float qs = (EPI == EPI_QKV && n0 < 1024) ? QSCALE : 1.0f;
#pragma unroll
  for (int i = 0; i < 4; ++i) {
#pragma unroll
    for (int r = 0; r < 4; ++r) {
      const int row = m0 + wm + 16*i + g4 + r;
#pragma unroll
      for (int j = 0; j < 4; ++j) {
        const int col = n0 + wn + 16*j + frow;
        const size_t idx = (size_t)row * ldc + col;
        float v = acc[i][j][r];
        if constexpr (EPI == EPI_RES) {
          v += (float)R[idx];
        } else if constexpr (EPI == EPI_GATE) {
          float up = b2f((unsigned short)R[idx]);
          v = up * (v / (1.f + __expf(-v)));
        } else if constexpr (EPI == EPI_QKV) {
          v *= qs;
        }
        if constexpr (sizeof(OutT) == 4) C[idx] = v;
        else                             C[idx] = f2b(v);
      }
    }
  }
}

// ---------------- Split-K GEMM: P_z[M,N] = A[M, z*Ks : (z+1)*Ks] @ B^T slice ----------------
__global__ __launch_bounds__(256)
void gemm_bt_splitk(const unsigned short* __restrict__ A,
                    const unsigned short* __restrict__ B,
                    float* __restrict__ P0, float* __restrict__ P1,
                    int M, int N, int K, int Ks) {
  __shared__ __align__(16) unsigned short As[128 * 32];
  __shared__ __align__(16) unsigned short Bs[128 * 32];
  const int tid = threadIdx.x;
  const int wave = tid >> 6;
  const int lane = tid & 63;
  const int m0 = blockIdx.y * 128;
  const int n0 = blockIdx.x * 128;
  const int z = blockIdx.z;
  float* C = z ? P1 : P0;
  const int kbase = z * Ks;
  const int wm = (wave & 1) * 64;
  const int wn = (wave >> 1) * 64;
  const int frow = lane & 15;
  const int fk = (lane >> 4) * 8;

  floatx4 acc[4][4];
#pragma unroll
  for (int i = 0; i < 4; ++i)
#pragma unroll
    for (int j = 0; j < 4; ++j) acc[i][j] = (floatx4){0.f, 0.f, 0.f, 0.f};

  const int srow = lane >> 2;
  const int scol = (lane & 3) * 8;
  const unsigned short* Ag  = A + (size_t)(m0 + wave * 16 + srow) * K + kbase + scol;
  const unsigned short* Ag2 = A + (size_t)(m0 + (wave + 4) * 16 + srow) * K + kbase + scol;
  const unsigned short* Bg  = B + (size_t)(n0 + wave * 16 + srow) * K + kbase + scol;
  const unsigned short* Bg2 = B + (size_t)(n0 + (wave + 4) * 16 + srow) * K + kbase + scol;

  for (int k0 = 0; k0 < Ks; k0 += 32) {
    __syncthreads();
    load_lds16(Ag + k0,  &As[wave * 512]);
    load_lds16(Ag2 + k0, &As[(wave + 4) * 512]);
    load_lds16(Bg + k0,  &Bs[wave * 512]);
    load_lds16(Bg2 + k0, &Bs[(wave + 4) * 512]);
    __syncthreads();
    short8 af[4], bf[4];
#pragma unroll
    for (int i = 0; i < 4; ++i) af[i] = *(const short8*)&As[(wm + 16*i + frow)*32 + fk];
#pragma unroll
    for (int j = 0; j < 4; ++j) bf[j] = *(const short8*)&Bs[(wn + 16*j + frow)*32 + fk];
#pragma unroll
    for (int i = 0; i < 4; ++i)
#pragma unroll
      for (int j = 0; j < 4; ++j)
        acc[i][j] = __builtin_amdgcn_mfma_f32_16x16x32_bf16(af[i], bf[j], acc[i][j], 0, 0, 0);
  }

  const int g4 = (lane >> 4) * 4;
#pragma unroll
  for (int i = 0; i < 4; ++i)
#pragma unroll
    for (int r = 0; r < 4; ++r) {
      const int row = m0 + wm + 16*i + g4 + r;
#pragma unroll
      for (int j = 0; j < 4; ++j) {
        const int col = n0 + wn + 16*j + frow;
        C[(size_t)row * N + col] = acc[i][j][r];
      }
    }
}

// ---------------- Fused up+gate GEMM: hup = up(x) * silu(gate(x)) ----------------
__global__ __launch_bounds__(256, 2)
void gemm_upgate(const unsigned short* __restrict__ A,
                 const unsigned short* __restrict__ Bu,
                 const unsigned short* __restrict__ Bg,
                 unsigned short* __restrict__ C, int M, int N, int K) {
  __shared__ __align__(16) unsigned short As[128 * 32];
  __shared__ __align__(16) unsigned short Bus[128 * 32];
  __shared__ __align__(16) unsigned short Bgs[128 * 32];
  const int tid = threadIdx.x;
  const int wave = tid >> 6;
  const int lane = tid & 63;
  const int m0 = blockIdx.y * 128;
  const int n0 = blockIdx.x * 128;
  const int wm = (wave & 1) * 64;
  const int wn = (wave >> 1) * 64;
  const int frow = lane & 15;
  const int fk = (lane >> 4) * 8;

  floatx4 au[4][4], ag[4][4];
#pragma unroll
  for (int i = 0; i < 4; ++i)
#pragma unroll
    for (int j = 0; j < 4; ++j) {
      au[i][j] = (floatx4){0.f, 0.f, 0.f, 0.f};
      ag[i][j] = (floatx4){0.f, 0.f, 0.f, 0.f};
    }

  const int srow = lane >> 2;
  const int scol = (lane & 3) * 8;
  const unsigned short* Ag1 = A  + (size_t)(m0 + wave * 16 + srow) * K + scol;
  const unsigned short* Ag2 = A  + (size_t)(m0 + (wave + 4) * 16 + srow) * K + scol;
  const unsigned short* Bu1 = Bu + (size_t)(n0 + wave * 16 + srow) * K + scol;
  const unsigned short* Bu2 = Bu + (size_t)(n0 + (wave + 4) * 16 + srow) * K + scol;
  const unsigned short* Bg1 = Bg + (size_t)(n0 + wave * 16 + srow) * K + scol;
  const unsigned short* Bg2 = Bg + (size_t)(n0 + (wave + 4) * 16 + srow) * K + scol;

  for (int k0 = 0; k0 < K; k0 += 32) {
    __syncthreads();
    load_lds16(Ag1 + k0, &As[wave * 512]);
    load_lds16(Ag2 + k0, &As[(wave + 4) * 512]);
    load_lds16(Bu1 + k0, &Bus[wave * 512]);
    load_lds16(Bu2 + k0, &Bus[(wave + 4) * 512]);
    load_lds16(Bg1 + k0, &Bgs[wave * 512]);
    load_lds16(Bg2 + k0, &Bgs[(wave + 4) * 512]);
    __syncthreads();
    short8 af[4], bu[4], bg[4];
#pragma unroll
    for (int i = 0; i < 4; ++i) af[i] = *(const short8*)&As[(wm + 16*i + frow)*32 + fk];
#pragma unroll
    for (int j = 0; j < 4; ++j) {
      bu[j] = *(const short8*)&Bus[(wn + 16*j + frow)*32 + fk];
      bg[j] = *(const short8*)&Bgs[(wn + 16*j + frow)*32 + fk];
    }
#pragma unroll
    for (int i = 0; i < 4; ++i)
#pragma unroll
      for (int j = 0; j < 4; ++j) {
        au[i][j] = __builtin_amdgcn_mfma_f32_16x16x32_bf16(af[i], bu[j], au[i][j], 0, 0, 0);
        ag[i][j] = __builtin_amdgcn_mfma_f32_16x16x32_bf16(af[i], bg[j], ag[i][j], 0, 0, 0);
      }
  }

  const int g4 = (lane >> 4) * 4;
#pragma unroll
  for (int i = 0; i < 4; ++i) {
#pragma unroll
    for (int r = 0; r < 4; ++r) {
      const int row = m0 + wm + 16*i + g4 + r;
#pragma unroll
      for (int j = 0; j < 4; ++j) {
        const int col = n0 + wn + 16*j + frow;
        float g = ag[i][j][r];
        float v = au[i][j][r] * (g / (1.f + __expf(-g)));
        C[(size_t)row * N + col] = f2b(v);
      }
    }
  }
}

// ---------------- Flash attention (causal), dh=64, S^T form, LDS-staged ----------------
__global__ __launch_bounds__(256, 2)
void attn_kernel(const unsigned short* __restrict__ qkv,  // [B*S, 2048] bf16: Q(scaled),K
                 const unsigned short* __restrict__ vt,   // [B*1024, 2048] bf16: V^T
                 unsigned short* __restrict__ out) {      // [B*S, 1024] bf16
  const int lin = blockIdx.x;
  const int bh = lin & 31;
  const int q_idx = lin >> 5;                        // 0..15
  const int qblk = (q_idx < 8) ? (2 * q_idx) : (31 - 2 * q_idx);
  const int b = bh >> 4, h = bh & 15;
  const int tid = threadIdx.x, w = tid >> 6, lane = tid & 63;
  const int f = lane & 15, g = lane >> 4;
  const int fk = g * 8, g4 = g * 4;

  __shared__ __align__(16) unsigned short Ks[2][128 * 32];  // [kq][key][32]: 16 KB
  __shared__ __align__(16) unsigned short Vs[4][64 * 32];   // [c][d][32]:    16 KB
  __shared__ __align__(16) unsigned int   pl[4][64 * 36];   // per-wave P^T:  36 KB

  const unsigned short* Qb = qkv + (size_t)(b * 2048) * 2048 + h * 64;
  const unsigned short* Kb = Qb + 1024;
  const unsigned short* Vt = vt + ((size_t)(b * 16 + h) * 64) * 2048;

  const int q0 = qblk * 128 + w * 32;
  short8 qf[2][2];
#pragma unroll
  for (int i = 0; i < 2; ++i)
#pragma unroll
    for (int kq = 0; kq < 2; ++kq)
      qf[i][kq] = *(const short8*)(Qb + (size_t)(q0 + 16*i + f) * 2048 + kq * 32 + fk);

  float m_s[2] = {-1e30f, -1e30f}, l_s[2] = {0.f, 0.f};
  floatx4 o[4][2];
#pragma unroll
  for (int mt = 0; mt < 4; ++mt)
#pragma unroll
    for (int i = 0; i < 2; ++i) o[mt][i] = (floatx4){0.f, 0.f, 0.f, 0.f};

  const int srow = lane >> 2;
  const int scol = (lane & 3) * 8;
  unsigned int* plw = pl[w];

  for (int kb = 0; kb <= qblk; ++kb) {
    __syncthreads();
#pragma unroll
    for (int u = 0; u < 2; ++u) {
      const int seg = w + 4 * u;
#pragma unroll
      for (int kq = 0; kq < 2; ++kq)
        load_lds16(Kb + (size_t)(kb * 128 + seg * 16 + srow) * 2048 + kq * 32 + scol,
                   &Ks[kq][seg * 512]);
    }
#pragma unroll
    for (int c = 0; c < 4; ++c)
      load_lds16(Vt + (size_t)(w * 16 + srow) * 2048 + kb * 128 + c * 32 + scol,
                 &Vs[c][w * 512]);
    __syncthreads();

    const bool diag = (kb == qblk);
    const int jhi0 = diag ? 2 * w : 7;
    const int jhi1 = diag ? 2 * w + 1 : 7;

    floatx4 s[8][2];
#pragma unroll
    for (int j = 0; j < 8; ++j) {
      if (j > jhi1) continue;
      short8 kf0 = *(const short8*)&Ks[0][(16*j + f) * 32 + fk];
      short8 kf1 = *(const short8*)&Ks[1][(16*j + f) * 32 + fk];
#pragma unroll
      for (int i = 0; i < 2; ++i) {
        if (j > (i ? jhi1 : jhi0)) continue;
        s[j][i] = (floatx4){0.f, 0.f, 0.f, 0.f};
        s[j][i] = __builtin_amdgcn_mfma_f32_16x16x32_bf16(kf0, qf[i][0], s[j][i], 0, 0, 0);
        s[j][i] = __builtin_amdgcn_mfma_f32_16x16x32_bf16(kf1, qf[i][1], s[j][i], 0, 0, 0);
      }
    }
    if (diag) {
#pragma unroll
      for (int i = 0; i < 2; ++i) {
        const int qo = 32 * w + 16 * i + f;
        const int jh = i ? jhi1 : jhi0;
#pragma unroll
        for (int j = 0; j < 8; ++j) {
          if (j > jh) continue;
#pragma unroll
          for (int r = 0; r < 4; ++r)
            if (16 * j + g4 + r > qo) s[j][i][r] = -1e30f;
        }
      }
    }
#pragma unroll
    for (int i = 0; i < 2; ++i) {
      const int jh = i ? jhi1 : jhi0;
      float mx = -1e30f;
#pragma unroll
      for (int j = 0; j < 8; ++j) {
        if (j > jh) continue;
#pragma unroll
        for (int r = 0; r < 4; ++r) mx = fmaxf(mx, s[j][i][r]);
      }
      mx = fmaxf(mx, __shfl_xor(mx, 16));
      mx = fmaxf(mx, __shfl_xor(mx, 32));
      const float mnew = fmaxf(m_s[i], mx);
      const float alpha = exp2f(m_s[i] - mnew);
      float rs = 0.f;
#pragma unroll
      for (int j = 0; j < 8; ++j) {
        if (j > jh) continue;
#pragma unroll
        for (int r = 0; r < 4; ++r) {
          float pv = exp2f(s[j][i][r] - mnew);
          s[j][i][r] = pv;
          rs += pv;
        }
      }
      rs += __shfl_xor(rs, 16);
      rs += __shfl_xor(rs, 32);
      l_s[i] = l_s[i] * alpha + rs;
      m_s[i] = mnew;
#pragma unroll
      for (int mt = 0; mt < 4; ++mt) o[mt][i] *= alpha;
    }
#pragma unroll
    for (int i = 0; i < 2; ++i) {
      const int jh = i ? jhi1 : jhi0;
#pragma unroll
      for (int j = 0; j < 8; ++j) {
        if (j > jh) continue;
        plw[(8*j + 2*g + 0) * 36 + 16*i + f] = f2b2(s[j][i][0], s[j][i][1]);
        plw[(8*j + 2*g + 1) * 36 + 16*i + f] = f2b2(s[j][i][2], s[j][i][3]);
      }
    }
    if (diag) {
      plw[(8*(2*w + 1) + 2*g + 0) * 36 + f] = 0u;
      plw[(8*(2*w + 1) + 2*g + 1) * 36 + f] = 0u;
    }
    const int chi = diag ? w : 3;
#pragma unroll
    for (int c = 0; c < 4; ++c) {
      if (c > chi) continue;
      union { unsigned int d[4]; short8 v; } pb[2];
#pragma unroll
      for (int i = 0; i < 2; ++i)
#pragma unroll
        for (int k = 0; k < 4; ++k)
          pb[i].d[k] = plw[(16*c + 4*g + k) * 36 + 16*i + f];
#pragma unroll
      for (int mt = 0; mt < 4; ++mt) {
        short8 va = *(const short8*)&Vs[c][(16*mt + f) * 32 + fk];
#pragma unroll
        for (int i = 0; i < 2; ++i)
          o[mt][i] = __builtin_amdgcn_mfma_f32_16x16x32_bf16(va, pb[i].v, o[mt][i], 0, 0, 0);
      }
    }
  }

#pragma unroll
  for (int i = 0; i < 2; ++i) {
    const float inv = 1.0f / l_s[i];
    unsigned short* orow = out + (size_t)(b * 2048 + q0 + 16*i + f) * 1024 + h * 64;
#pragma unroll
    for (int mt = 0; mt < 4; ++mt) {
      ushort4 ov;
      ov.x = f2b(o[mt][i][0] * inv);
      ov.y = f2b(o[mt][i][1] * inv);
      ov.z = f2b(o[mt][i][2] * inv);
      ov.w = f2b(o[mt][i][3] * inv);
      *(ushort4*)(orow + 16 * mt + g4) = ov;
    }
  }
}

// ---------------- launcher ----------------
extern "C" void kernel_launch(void* const* d_in, const int* in_sizes, int n_in,
                              void* d_out, int out_size, void* d_ws, size_t ws_size,
                              hipStream_t stream) {
  const float* x      = (const float*)d_in[0];   // [2,2048,1024]
  const float* w_qkv  = (const float*)d_in[1];   // [3072,1024]
  const float* w_o    = (const float*)d_in[2];   // [1024,1024]
  const float* w_up   = (const float*)d_in[3];   // [4096,1024]
  const float* w_gate = (const float*)d_in[4];   // [4096,1024]
  const float* w_down = (const float*)d_in[5];   // [1024,4096]
  const float* scale1 = (const float*)d_in[6];
  const float* scale2 = (const float*)d_in[7];

  char* ws = (char*)d_ws;
  unsigned short* wq_b = (unsigned short*)(ws);                 //  6,291,456 B
  unsigned short* wo_b = (unsigned short*)(ws +  6291456);      //  2,097,152 B
  unsigned short* wu_b = (unsigned short*)(ws +  8388608);      //  8,388,608 B
  unsigned short* wg_b = (unsigned short*)(ws + 16777216);      //  8,388,608 B
  unsigned short* wd_b = (unsigned short*)(ws + 25165824);      //  8,388,608 B
  unsigned short* qkv  = (unsigned short*)(ws + 33554432);      // 16,777,216 B (Q,K; ldc 2048)
  unsigned short* hup  = (unsigned short*)(ws + 33554432);      // 33,554,432 B (aliases qkv+vT+attnb)
  unsigned short* vT   = (unsigned short*)(ws + 50331648);      //  8,388,608 B (V^T)
  unsigned short* attnb= (unsigned short*)(ws + 58720256);      //  8,388,608 B
  unsigned short* xn   = (unsigned short*)(ws + 67108864);      //  8,388,608 B
  float*          x1   = (float*)         (ws + 75497472);      // 16,777,216 B (fp32)
  float*          outp = (float*)d_out;                         // fp32

  // split-K partials (aliased over dead regions at their point of use):
  float* wo_p0   = (float*)(ws + 33554432);  // over qkv (dead after attn)
  float* wo_p1   = (float*)d_out;            // d_out unused until MLP end
  float* down_p0 = (float*)d_out;            // slice 0 -> d_out
  float* down_p1 = (float*)(ws + 8388608);   // over wu_b+wg_b (dead after upgate)

  const int M = 4096;
  dim3 blk(256);

  // all weights fp32 -> bf16 in one dispatch (4,194,304 float4s)
  cvt_all_kernel<<<16384, blk, 0, stream>>>(w_qkv, w_o, w_up, w_gate, w_down,
                                            wq_b, wo_b, wu_b, wg_b, wd_b);

  // x1 = x + W_o( attn( rms(x) ) )    [W_o via split-K, reduce fused into rmsnorm_res2]
  rmsnorm_kernel<<<4096, blk, 0, stream>>>(x, scale1, xn);
  gemm_bt<EPI_QKV, unsigned short, unsigned short>
      <<<dim3(24, 32), blk, 0, stream>>>(xn, wq_b, qkv, (const unsigned short*)nullptr, vT,
                                         M, 3072, 1024, 2048);
  attn_kernel<<<dim3(512), blk, 0, stream>>>(qkv, vT, attnb);
  gemm_bt_splitk<<<dim3(8, 32, 2), blk, 0, stream>>>(attnb, wo_b, wo_p0, wo_p1,
                                                     M, 1024, 1024, 512);

  // x1 = x + p0 + p1 ; xn = rms(x1)
  rmsnorm_res2_kernel<<<4096, blk, 0, stream>>>(x, wo_p0, wo_p1, scale2, x1, xn);

  // out = x1 + W_down( up(rms) * silu(gate(rms)) )   [W_down via split-K]
  gemm_upgate<<<dim3(32, 32), blk, 0, stream>>>(xn, wu_b, wg_b, hup, M, 4096, 1024);
  gemm_bt_splitk<<<dim3(8, 32, 2), blk, 0, stream>>>(hup, wd_b, down_p0, down_p1,
                                                     M, 1024, 4096, 2048);
  reduce_out_kernel<<<4096, blk, 0, stream>>>(x1, down_p1, outp);

  (void)in_sizes; (void)n_in; (void)out_size; (void)ws_size;
}